// Round 3
// baseline (12779.164 us; speedup 1.0000x reference)
//
#include <hip/hip_runtime.h>
#include <hip/hip_bf16.h>
#include <math.h>

#define NNODES 262144
#define NEDGES 524288
#define NSEG   512      // B*C segments

typedef __hip_bfloat16 bf16;

__device__ __forceinline__ float ldf(const float* p, size_t i) { return p[i]; }
__device__ __forceinline__ float ldf(const bf16*  p, size_t i) { return __bfloat162float(p[i]); }

// ---------------------------------------------------------------------------
// Generic fused GEMM: out[n, :OUT] = res + act( A[n, :K] @ W + bias )
//   A is a virtual concat of up to 3 row-major segments (all dtype TA):
//     seg0: A0 [N, w0]
//     seg1: A1 [*, w1]   (if gidx != null: row = gidx[n]  -> embedding gather)
//     seg2: A2 [N, w2]
//     (k >= w0+w1+w2  -> 0, handles K not multiple of 32)
//   W is a virtual row-stack: rows [0,kw) from Wa, rows [kw,K) from Wb (fp32).
//   act = leaky_relu(alpha); alpha=1.0 -> identity. res (bf16, nullable) added
//   AFTER act. out is bf16. Accumulation fully fp32.
// Tile: 64 rows x 64 cols, 256 threads, 4x4 microtile, BK=32.
// ---------------------------------------------------------------------------
template<typename TA>
__global__ __launch_bounds__(256) void gemm_tile(
    const TA* __restrict__ A0, int w0,
    const TA* __restrict__ A1, int w1,
    const TA* __restrict__ A2, int w2,
    const int*   __restrict__ gidx,
    const float* __restrict__ Wa, int kw,
    const float* __restrict__ Wb,
    const float* __restrict__ bias,
    const bf16*  __restrict__ res,
    bf16* __restrict__ out,
    int K, int OUT, float alpha)
{
    __shared__ float As[32][68];   // k-major; 68*4=272B row pitch (16B-aligned)
    __shared__ float Ws[32][64];

    const int tid  = threadIdx.x;
    const int ty   = tid >> 4;     // 0..15 (row group)
    const int tx   = tid & 15;     // 0..15 (col group)
    const int row0 = blockIdx.y * 64;
    const int col0 = blockIdx.x * 64;

    float acc[4][4];
    #pragma unroll
    for (int j = 0; j < 4; ++j)
        #pragma unroll
        for (int i = 0; i < 4; ++i) acc[j][i] = 0.f;

    for (int k0 = 0; k0 < K; k0 += 32) {
        // ---- stage A tile (64 rows x 32 k), global-coalesced along k ----
        #pragma unroll
        for (int i = 0; i < 8; ++i) {
            int f  = i * 256 + tid;
            int kk = f & 31;
            int r  = f >> 5;
            int n  = row0 + r;
            int gk = k0 + kk;
            float v;
            if (gk < w0) {
                v = ldf(A0, (size_t)n * w0 + gk);
            } else {
                int k1 = gk - w0;
                if (k1 < w1) {
                    int rr = gidx ? gidx[n] : n;
                    v = ldf(A1, (size_t)rr * w1 + k1);
                } else {
                    int k2 = k1 - w1;
                    v = (k2 < w2) ? ldf(A2, (size_t)n * w2 + k2) : 0.f;
                }
            }
            As[kk][r] = v;
        }
        // ---- stage W tile (32 k x 64 cols), fp32 ----
        #pragma unroll
        for (int i = 0; i < 8; ++i) {
            int f  = i * 256 + tid;
            int kk = f >> 6;
            int c  = f & 63;
            int gk = k0 + kk;
            int gc = col0 + c;
            float v = 0.f;
            if (gk < K && gc < OUT)
                v = (gk < kw) ? Wa[(size_t)gk * OUT + gc]
                              : Wb[(size_t)(gk - kw) * OUT + gc];
            Ws[kk][c] = v;
        }
        __syncthreads();
        // ---- 32 x (2 lds vec reads + 16 fma) ----
        #pragma unroll
        for (int kk = 0; kk < 32; ++kk) {
            const float4 a = *(const float4*)&As[kk][ty * 4];
            const float4 b = *(const float4*)&Ws[kk][tx * 4];
            acc[0][0] += a.x * b.x; acc[0][1] += a.x * b.y; acc[0][2] += a.x * b.z; acc[0][3] += a.x * b.w;
            acc[1][0] += a.y * b.x; acc[1][1] += a.y * b.y; acc[1][2] += a.y * b.z; acc[1][3] += a.y * b.w;
            acc[2][0] += a.z * b.x; acc[2][1] += a.z * b.y; acc[2][2] += a.z * b.z; acc[2][3] += a.z * b.w;
            acc[3][0] += a.w * b.x; acc[3][1] += a.w * b.y; acc[3][2] += a.w * b.z; acc[3][3] += a.w * b.w;
        }
        __syncthreads();
    }
    // ---- epilogue: bias + leaky + residual, store bf16 ----
    #pragma unroll
    for (int j = 0; j < 4; ++j) {
        int r = row0 + ty * 4 + j;
        #pragma unroll
        for (int i = 0; i < 4; ++i) {
            int c = col0 + tx * 4 + i;
            if (c < OUT) {
                float v = acc[j][i] + bias[c];
                v = (v > 0.f) ? v : alpha * v;
                if (res) v += __bfloat162float(res[(size_t)r * OUT + c]);
                out[(size_t)r * OUT + c] = __float2bfloat16(v);
            }
        }
    }
}

// ---------------------------------------------------------------------------
// config-feature MLP: 14 -> 14 (lrelu .01) -> 64 (lrelu .01), one thread/node
// ---------------------------------------------------------------------------
__global__ __launch_bounds__(256) void cf_mlp(
    const float* __restrict__ ncf,
    const float* __restrict__ w1, const float* __restrict__ b1,
    const float* __restrict__ w2, const float* __restrict__ b2,
    bf16* __restrict__ cf)
{
    __shared__ float W1s[196], B1s[14], W2s[896], B2s[64];
    int t = threadIdx.x;
    for (int i = t; i < 196; i += 256) W1s[i] = w1[i];
    for (int i = t; i < 896; i += 256) W2s[i] = w2[i];
    if (t < 14) B1s[t] = b1[t];
    if (t >= 32 && t < 96) B2s[t - 32] = b2[t - 32];
    __syncthreads();

    int n = blockIdx.x * 256 + t;
    float in[14], hid[14];
    #pragma unroll
    for (int k = 0; k < 14; ++k) in[k] = ncf[(size_t)n * 14 + k];
    #pragma unroll
    for (int j = 0; j < 14; ++j) {
        float s = B1s[j];
        #pragma unroll
        for (int k = 0; k < 14; ++k) s += in[k] * W1s[k * 14 + j];
        hid[j] = (s > 0.f) ? s : 0.01f * s;
    }
    #pragma unroll 4
    for (int j = 0; j < 64; ++j) {
        float s = B2s[j];
        #pragma unroll
        for (int k = 0; k < 14; ++k) s += hid[k] * W2s[k * 64 + j];
        s = (s > 0.f) ? s : 0.01f * s;
        cf[(size_t)n * 64 + j] = __float2bfloat16(s);
    }
}

// ---------------------------------------------------------------------------
// CSR build: zero -> indeg count -> 3-phase exclusive scan -> scatter
// ---------------------------------------------------------------------------
__global__ void zero_ints(int* __restrict__ p, int n)
{
    int i = blockIdx.x * 256 + threadIdx.x;
    if (i < n) p[i] = 0;
}

__global__ void count_deg(const int* __restrict__ dst, int* __restrict__ indeg)
{
    int e = blockIdx.x * 256 + threadIdx.x;
    atomicAdd(&indeg[dst[e]], 1);
}

__global__ __launch_bounds__(256) void scan_block(
    const int* __restrict__ in, int* __restrict__ part, int* __restrict__ bsums)
{
    __shared__ int sh[256];
    int t = threadIdx.x, b = blockIdx.x;
    int base = b * 1024 + t * 4;
    int v0 = in[base], v1 = in[base + 1], v2 = in[base + 2], v3 = in[base + 3];
    int s = v0 + v1 + v2 + v3;
    sh[t] = s; __syncthreads();
    #pragma unroll
    for (int off = 1; off < 256; off <<= 1) {
        int x = (t >= off) ? sh[t - off] : 0;
        __syncthreads();
        sh[t] += x;
        __syncthreads();
    }
    int excl = sh[t] - s;
    if (t == 255) bsums[b] = sh[t];
    part[base]     = excl;
    part[base + 1] = excl + v0;
    part[base + 2] = excl + v0 + v1;
    part[base + 3] = excl + v0 + v1 + v2;
}

__global__ __launch_bounds__(256) void scan_tops(int* __restrict__ bsums)
{
    __shared__ int sh[256];
    int t = threadIdx.x;
    int s = bsums[t];
    sh[t] = s; __syncthreads();
    #pragma unroll
    for (int off = 1; off < 256; off <<= 1) {
        int x = (t >= off) ? sh[t - off] : 0;
        __syncthreads();
        sh[t] += x;
        __syncthreads();
    }
    bsums[t] = sh[t] - s;   // exclusive
}

__global__ void scan_fix(int* __restrict__ offsets, const int* __restrict__ bsums,
                         int* __restrict__ cursor)
{
    int i = blockIdx.x * 256 + threadIdx.x;
    int v = offsets[i] + bsums[i >> 10];
    offsets[i] = v;
    cursor[i]  = v;
    if (i == 0) offsets[NNODES] = NEDGES;
}

__global__ void scatter_edges(const int* __restrict__ src, const int* __restrict__ dst,
                              int* __restrict__ cursor, int* __restrict__ csr)
{
    int e = blockIdx.x * 256 + threadIdx.x;
    int pos = atomicAdd(&cursor[dst[e]], 1);
    csr[pos] = src[e];
}

// ---------------------------------------------------------------------------
// SAGE max-aggregation: one wave per dst node; y = concat(cf, h) read on the fly.
// Empty in-neighborhood -> 0 (matches isfinite-replace in reference).
// max over bf16 values is exact; stored back as bf16.
// ---------------------------------------------------------------------------
__global__ __launch_bounds__(256) void sage_agg(
    const int* __restrict__ offsets, const int* __restrict__ csr,
    const bf16* __restrict__ cf, const bf16* __restrict__ h,
    bf16* __restrict__ agg)
{
    int wid = threadIdx.x >> 6, lane = threadIdx.x & 63;
    int n = blockIdx.x * 4 + wid;
    int beg = offsets[n], end = offsets[n + 1];
    float m0 = -3.4e38f, m1 = m0, m2 = m0, m3 = m0;
    for (int e = beg; e < end; ++e) {
        int s = csr[e];
        m0 = fmaxf(m0, __bfloat162float(cf[(size_t)s * 64 + lane]));
        const bf16* hr = h + (size_t)s * 192;
        m1 = fmaxf(m1, __bfloat162float(hr[lane]));
        m2 = fmaxf(m2, __bfloat162float(hr[64 + lane]));
        m3 = fmaxf(m3, __bfloat162float(hr[128 + lane]));
    }
    if (beg == end) { m0 = m1 = m2 = m3 = 0.f; }
    bf16* ar = agg + (size_t)n * 256;
    ar[lane]       = __float2bfloat16(m0);
    ar[64 + lane]  = __float2bfloat16(m1);
    ar[128 + lane] = __float2bfloat16(m2);
    ar[192 + lane] = __float2bfloat16(m3);
}

// ---------------------------------------------------------------------------
// per-segment sum pool over h [N,192] + fc dot -> scores [512]
// ---------------------------------------------------------------------------
__global__ __launch_bounds__(256) void pool_fc(
    const bf16* __restrict__ h, const int* __restrict__ sep,
    const float* __restrict__ fc_w, float* __restrict__ out)
{
    __shared__ float red[256];
    int b = blockIdx.x, t = threadIdx.x;
    int r0 = (b == 0) ? 0 : sep[b - 1];
    int r1 = sep[b];
    float s0 = 0.f, s1 = 0.f, s2 = 0.f, s3 = 0.f;
    if (t < 192) {
        int r = r0;
        for (; r + 3 < r1; r += 4) {
            s0 += __bfloat162float(h[(size_t)r * 192 + t]);
            s1 += __bfloat162float(h[(size_t)(r + 1) * 192 + t]);
            s2 += __bfloat162float(h[(size_t)(r + 2) * 192 + t]);
            s3 += __bfloat162float(h[(size_t)(r + 3) * 192 + t]);
        }
        for (; r < r1; ++r) s0 += __bfloat162float(h[(size_t)r * 192 + t]);
    }
    red[t] = (t < 192) ? (s0 + s1 + s2 + s3) * fc_w[t] : 0.f;
    __syncthreads();
    #pragma unroll
    for (int st = 128; st > 0; st >>= 1) {
        if (t < st) red[t] += red[t + st];
        __syncthreads();
    }
    if (t == 0) out[b] = red[0];
}

// diagnostic: report ws_size (MiB) through the output if workspace too small
__global__ void report_ws(float* __restrict__ out, float mb)
{
    out[blockIdx.x * 256 + threadIdx.x] = mb;
}

// ---------------------------------------------------------------------------
extern "C" void kernel_launch(void* const* d_in, const int* in_sizes, int n_in,
                              void* d_out, int out_size, void* d_ws, size_t ws_size,
                              hipStream_t stream)
{
    const float* node_features = (const float*)d_in[0];
    const float* node_config   = (const float*)d_in[1];
    const int*   node_sep      = (const int*)d_in[2];
    const int*   node_ops      = (const int*)d_in[3];
    const int*   edges         = (const int*)d_in[4];
    // d_in[5] = batches (unused by the reference math)
    const float* emb    = (const float*)d_in[6];
    const float* nf_w1  = (const float*)d_in[7];
    const float* nf_b1  = (const float*)d_in[8];
    const float* nf_w2  = (const float*)d_in[9];
    const float* nf_b2  = (const float*)d_in[10];
    const float* cf_w1  = (const float*)d_in[11];
    const float* cf_b1  = (const float*)d_in[12];
    const float* cf_w2  = (const float*)d_in[13];
    const float* cf_b2  = (const float*)d_in[14];
    const float* pre_w1 = (const float*)d_in[15];
    const float* pre_b1 = (const float*)d_in[16];
    const float* pre_w2 = (const float*)d_in[17];
    const float* pre_b2 = (const float*)d_in[18];
    const float* sage_wl= (const float*)d_in[19];
    const float* sage_bl= (const float*)d_in[20];
    const float* sage_wr= (const float*)d_in[21];
    const float* mlp_w1 = (const float*)d_in[22];
    const float* mlp_b1 = (const float*)d_in[23];
    const float* mlp_w2 = (const float*)d_in[24];
    const float* mlp_b2 = (const float*)d_in[25];
    const float* fc_w   = (const float*)d_in[26];

    const size_t N = NNODES;

    // workspace (bf16 activations): cf(64) | h(192) | bufA(256) | bufB(256),
    // then CSR ints. bufA holds t1/t2/agg; bufB holds x/z.  ~389 MiB total.
    const size_t fl_bytes  = N * 768 * sizeof(bf16);
    const size_t int_elems = (N + 1) + N + N + NEDGES + 256;
    const size_t needed    = fl_bytes + int_elems * 4;
    if (ws_size < needed) {
        // debug channel: absmax will read ~= ws_size in MiB
        report_ws<<<2, 256, 0, stream>>>((float*)d_out,
                                         (float)((double)ws_size / 1048576.0));
        return;
    }

    bf16* cf   = (bf16*)d_ws;                   // [N,64]
    bf16* h    = cf   + N * 64;                 // [N,192]
    bf16* bufA = h    + N * 192;                // [N,256]
    bf16* bufB = bufA + N * 256;                // [N,256]
    int* offsets = (int*)(bufB + N * 256);      // [N+1]  (byte offset N*1536, 4-aligned)
    int* indeg   = offsets + (N + 1);           // [N]
    int* cursor  = indeg + N;                   // [N]
    int* csr     = cursor + N;                  // [E]
    int* bsums   = csr + NEDGES;                // [256]

    const int* esrc = edges;            // edges[0, :]
    const int* edst = edges + NEDGES;   // edges[1, :]

    dim3 blk(256);

    // config-feature MLP -> cf [N,64]
    cf_mlp<<<NNODES / 256, blk, 0, stream>>>(node_config, cf_w1, cf_b1, cf_w2, cf_b2, cf);

    // node-feature MLP: concat(nf, emb[ops]) @ nf_w1 -> bufA(t1) ; @ nf_w2 -> bufB(x)
    gemm_tile<float><<<dim3(3, NNODES / 64), blk, 0, stream>>>(
        node_features, 112, emb, 64, nullptr, 0, node_ops,
        nf_w1, 176, nullptr, nf_b1, nullptr, bufA, 176, 176, 0.01f);
    gemm_tile<bf16><<<dim3(3, NNODES / 64), blk, 0, stream>>>(
        bufA, 176, nullptr, 0, nullptr, 0, nullptr,
        nf_w2, 176, nullptr, nf_b2, nullptr, bufB, 176, 192, 0.01f);

    // prenet: concat(cf, x=bufB) @ pre_w1 -> bufA(t2) ; bufA @ pre_w2 -> h
    gemm_tile<bf16><<<dim3(3, NNODES / 64), blk, 0, stream>>>(
        cf, 64, bufB, 192, nullptr, 0, nullptr,
        pre_w1, 256, nullptr, pre_b1, nullptr, bufA, 256, 192, 0.2f);
    gemm_tile<bf16><<<dim3(3, NNODES / 64), blk, 0, stream>>>(
        bufA, 192, nullptr, 0, nullptr, 0, nullptr,
        pre_w2, 192, nullptr, pre_b2, nullptr, h, 192, 192, 0.2f);

    // CSR build (same work every call; ws is re-poisoned each timed launch)
    zero_ints<<<NNODES / 256, blk, 0, stream>>>(indeg, NNODES);
    count_deg<<<NEDGES / 256, blk, 0, stream>>>(edst, indeg);
    scan_block<<<NNODES / 1024, blk, 0, stream>>>(indeg, offsets, bsums);
    scan_tops<<<1, blk, 0, stream>>>(bsums);
    scan_fix<<<NNODES / 256, blk, 0, stream>>>(offsets, bsums, cursor);
    scatter_edges<<<NEDGES / 256, blk, 0, stream>>>(esrc, edst, cursor, csr);

    // 2 x (SAGE-max + MLP + residual)
    for (int l = 0; l < 2; ++l) {
        sage_agg<<<NNODES / 4, blk, 0, stream>>>(offsets, csr, cf, h, bufA);
        // z = agg@Wl + concat(cf,h)@Wr + bl   (single K=512 GEMM, identity act)
        gemm_tile<bf16><<<dim3(4, NNODES / 64), blk, 0, stream>>>(
            bufA, 256, cf, 64, h, 192, nullptr,
            sage_wl + (size_t)l * 256 * 256, 256, sage_wr + (size_t)l * 256 * 256,
            sage_bl + (size_t)l * 256, nullptr, bufB, 512, 256, 1.0f);
        // t2 = lrelu.2(z @ mlp_w1 + b1)  -> bufA
        gemm_tile<bf16><<<dim3(3, NNODES / 64), blk, 0, stream>>>(
            bufB, 256, nullptr, 0, nullptr, 0, nullptr,
            mlp_w1 + (size_t)l * 256 * 192, 256, nullptr,
            mlp_b1 + (size_t)l * 192, nullptr, bufA, 256, 192, 0.2f);
        // h = h + lrelu.2(t2 @ mlp_w2 + b2)   (in-place residual)
        gemm_tile<bf16><<<dim3(3, NNODES / 64), blk, 0, stream>>>(
            bufA, 192, nullptr, 0, nullptr, 0, nullptr,
            mlp_w2 + (size_t)l * 192 * 192, 192, nullptr,
            mlp_b2 + (size_t)l * 192, h, h, 192, 192, 0.2f);
    }

    // pooled segment sums + fc -> scores [512]
    pool_fc<<<NSEG, blk, 0, stream>>>(h, node_sep, fc_w, (float*)d_out);
}

// Round 5
// 2242.353 us; speedup vs baseline: 5.6990x; 5.6990x over previous
//
#include <hip/hip_runtime.h>
#include <hip/hip_bf16.h>
#include <math.h>

#define NNODES 262144
#define NEDGES 524288
#define NSEG   512      // B*C segments

typedef __hip_bfloat16 bf16;
typedef __attribute__((ext_vector_type(8))) short short8;   // 8 bf16 = 4 VGPR
typedef __attribute__((ext_vector_type(4))) float f32x4;

__device__ __forceinline__ short bfbits(float f) {
    return __builtin_bit_cast(short, (__bf16)f);
}

// load 8 contiguous virtual-K elements as bf16 bits (16B-aligned: all widths %8==0)
__device__ __forceinline__ short8 ld8(const bf16* p, size_t off) {
    return *(const short8*)((const short*)p + off);
}
__device__ __forceinline__ short8 ld8(const float* p, size_t off) {
    const float4* q = (const float4*)(p + off);
    float4 a = q[0], b = q[1];
    short8 r;
    r[0] = bfbits(a.x); r[1] = bfbits(a.y); r[2] = bfbits(a.z); r[3] = bfbits(a.w);
    r[4] = bfbits(b.x); r[5] = bfbits(b.y); r[6] = bfbits(b.z); r[7] = bfbits(b.w);
    return r;
}

// ---------------------------------------------------------------------------
// Weight prep: Wt[OUT][K] bf16  <-  row-stack{Wa[0:kw), Wb[kw:K)} [K][OUT] fp32
// grid: (ceil(K/256), OUT)
// ---------------------------------------------------------------------------
__global__ void prep_wt(const float* __restrict__ Wa, int kw,
                        const float* __restrict__ Wb,
                        short* __restrict__ Wt, int K, int OUT)
{
    int k = blockIdx.x * 256 + threadIdx.x;
    int c = blockIdx.y;
    if (k < K) {
        float v = (k < kw) ? Wa[(size_t)k * OUT + c] : Wb[(size_t)(k - kw) * OUT + c];
        Wt[(size_t)c * K + k] = bfbits(v);
    }
}

// ---------------------------------------------------------------------------
// MFMA GEMM: out[n,:OUT] = res + lrelu_alpha( A[n,:K] @ W + bias ), W = Wt^T
//   A = virtual concat of up to 3 row-major segments (widths %8==0),
//   seg1 optionally gathered via gidx (embedding). K %8==0; zero-fill to BK.
// Tile: 128 rows x BN cols (BN = OUT padded to 192/256), BK=32, 256 thr,
// 4 waves 2x2, per wave 4 m-frags x BN/32 n-frags of mfma_f32_16x16x32_bf16.
// LDS rows padded to 40 bf16 (80B pitch -> <=2-way bank aliasing, free).
// ---------------------------------------------------------------------------
template<typename TA, int BN>
__global__ __launch_bounds__(256) void mfma_gemm(
    const TA* __restrict__ A0, int w0,
    const TA* __restrict__ A1, int w1,
    const TA* __restrict__ A2, int w2,
    const int*   __restrict__ gidx,
    const short* __restrict__ Wt,
    const float* __restrict__ bias,
    const bf16*  __restrict__ res,
    bf16* __restrict__ out,
    int K, int OUT, float alpha)
{
    constexpr int NRW = BN / 32;        // n-frags per wave (wave covers BN/2)
    __shared__ short As[128 * 40];
    __shared__ short Bs[BN * 40];
    __shared__ float biasLds[BN];

    const int tid  = threadIdx.x;
    const int lane = tid & 63;
    const int wid  = tid >> 6;
    const int row0 = blockIdx.x * 128;
    const int wr   = (wid >> 1) * 64;       // wave row offset
    const int wc   = (wid & 1) * (BN / 2);  // wave col offset
    const int fr   = lane & 15;             // frag row (A) / col (B,D)
    const int fc   = lane >> 4;             // k-chunk (A,B) / row-group (D)

    if (tid < BN) biasLds[tid] = (tid < OUT) ? bias[tid] : 0.f;

    f32x4 acc[NRW][4];
    #pragma unroll
    for (int nr = 0; nr < NRW; ++nr)
        #pragma unroll
        for (int m = 0; m < 4; ++m) acc[nr][m] = f32x4{0.f, 0.f, 0.f, 0.f};

    for (int k0 = 0; k0 < K; k0 += 32) {
        // ---- stage A tile: 128 rows x 32 k (bf16), 2 chunks/thread ----
        #pragma unroll
        for (int i = 0; i < 2; ++i) {
            int f  = i * 256 + tid;
            int r  = f >> 2;
            int kl = (f & 3) * 8;
            int gk = k0 + kl;
            short8 v{};
            if (gk < K) {
                int n = row0 + r;
                if (gk < w0) v = ld8(A0, (size_t)n * w0 + gk);
                else {
                    int k1 = gk - w0;
                    if (k1 < w1) {
                        int rr = gidx ? gidx[n] : n;
                        v = ld8(A1, (size_t)rr * w1 + k1);
                    } else {
                        v = ld8(A2, (size_t)n * w2 + (k1 - w1));
                    }
                }
            }
            *(short8*)&As[r * 40 + kl] = v;
        }
        // ---- stage B tile: BN cols x 32 k from Wt[OUT][K] ----
        #pragma unroll
        for (int i = 0; i < BN / 64; ++i) {
            int f  = i * 256 + tid;
            int c  = f >> 2;
            int kl = (f & 3) * 8;
            int gk = k0 + kl;
            short8 v{};
            if (gk < K && c < OUT) v = *(const short8*)&Wt[(size_t)c * K + gk];
            *(short8*)&Bs[c * 40 + kl] = v;
        }
        __syncthreads();
        // ---- compute: 4 A-frags, NRW B-frags, 4*NRW mfma ----
        short8 af[4];
        #pragma unroll
        for (int m = 0; m < 4; ++m)
            af[m] = *(short8*)&As[(wr + m * 16 + fr) * 40 + fc * 8];
        #pragma unroll
        for (int nr = 0; nr < NRW; ++nr) {
            short8 bfr = *(short8*)&Bs[(wc + nr * 16 + fr) * 40 + fc * 8];
            #pragma unroll
            for (int m = 0; m < 4; ++m)
                acc[nr][m] = __builtin_amdgcn_mfma_f32_16x16x32_bf16(
                    af[m], bfr, acc[nr][m], 0, 0, 0);
        }
        __syncthreads();
    }
    // ---- epilogue: bias + lrelu + residual, bf16 store ----
    #pragma unroll
    for (int nr = 0; nr < NRW; ++nr) {
        int c = wc + nr * 16 + fr;
        if (c < OUT) {
            float bv = biasLds[c];
            #pragma unroll
            for (int m = 0; m < 4; ++m) {
                #pragma unroll
                for (int j = 0; j < 4; ++j) {
                    int r = row0 + wr + m * 16 + fc * 4 + j;
                    float v = acc[nr][m][j] + bv;
                    v = (v > 0.f) ? v : alpha * v;
                    if (res) v += __bfloat162float(res[(size_t)r * OUT + c]);
                    out[(size_t)r * OUT + c] = __float2bfloat16(v);
                }
            }
        }
    }
}

// ---------------------------------------------------------------------------
// config-feature MLP: 14 -> 14 (lrelu .01) -> 64 (lrelu .01), one thread/node
// ---------------------------------------------------------------------------
__global__ __launch_bounds__(256) void cf_mlp(
    const float* __restrict__ ncf,
    const float* __restrict__ w1, const float* __restrict__ b1,
    const float* __restrict__ w2, const float* __restrict__ b2,
    bf16* __restrict__ cf)
{
    __shared__ float W1s[196], B1s[14], W2s[896], B2s[64];
    int t = threadIdx.x;
    for (int i = t; i < 196; i += 256) W1s[i] = w1[i];
    for (int i = t; i < 896; i += 256) W2s[i] = w2[i];
    if (t < 14) B1s[t] = b1[t];
    if (t >= 32 && t < 96) B2s[t - 32] = b2[t - 32];
    __syncthreads();

    int n = blockIdx.x * 256 + t;
    float in[14], hid[14];
    #pragma unroll
    for (int k = 0; k < 14; ++k) in[k] = ncf[(size_t)n * 14 + k];
    #pragma unroll
    for (int j = 0; j < 14; ++j) {
        float s = B1s[j];
        #pragma unroll
        for (int k = 0; k < 14; ++k) s += in[k] * W1s[k * 14 + j];
        hid[j] = (s > 0.f) ? s : 0.01f * s;
    }
    #pragma unroll 4
    for (int j = 0; j < 64; ++j) {
        float s = B2s[j];
        #pragma unroll
        for (int k = 0; k < 14; ++k) s += hid[k] * W2s[k * 64 + j];
        s = (s > 0.f) ? s : 0.01f * s;
        cf[(size_t)n * 64 + j] = __float2bfloat16(s);
    }
}

// ---------------------------------------------------------------------------
// CSR build: zero -> indeg count -> 3-phase exclusive scan -> scatter
// ---------------------------------------------------------------------------
__global__ void zero_ints(int* __restrict__ p, int n)
{
    int i = blockIdx.x * 256 + threadIdx.x;
    if (i < n) p[i] = 0;
}

__global__ void count_deg(const int* __restrict__ dst, int* __restrict__ indeg)
{
    int e = blockIdx.x * 256 + threadIdx.x;
    atomicAdd(&indeg[dst[e]], 1);
}

__global__ __launch_bounds__(256) void scan_block(
    const int* __restrict__ in, int* __restrict__ part, int* __restrict__ bsums)
{
    __shared__ int sh[256];
    int t = threadIdx.x, b = blockIdx.x;
    int base = b * 1024 + t * 4;
    int v0 = in[base], v1 = in[base + 1], v2 = in[base + 2], v3 = in[base + 3];
    int s = v0 + v1 + v2 + v3;
    sh[t] = s; __syncthreads();
    #pragma unroll
    for (int off = 1; off < 256; off <<= 1) {
        int x = (t >= off) ? sh[t - off] : 0;
        __syncthreads();
        sh[t] += x;
        __syncthreads();
    }
    int excl = sh[t] - s;
    if (t == 255) bsums[b] = sh[t];
    part[base]     = excl;
    part[base + 1] = excl + v0;
    part[base + 2] = excl + v0 + v1;
    part[base + 3] = excl + v0 + v1 + v2;
}

__global__ __launch_bounds__(256) void scan_tops(int* __restrict__ bsums)
{
    __shared__ int sh[256];
    int t = threadIdx.x;
    int s = bsums[t];
    sh[t] = s; __syncthreads();
    #pragma unroll
    for (int off = 1; off < 256; off <<= 1) {
        int x = (t >= off) ? sh[t - off] : 0;
        __syncthreads();
        sh[t] += x;
        __syncthreads();
    }
    bsums[t] = sh[t] - s;   // exclusive
}

__global__ void scan_fix(int* __restrict__ offsets, const int* __restrict__ bsums,
                         int* __restrict__ cursor)
{
    int i = blockIdx.x * 256 + threadIdx.x;
    int v = offsets[i] + bsums[i >> 10];
    offsets[i] = v;
    cursor[i]  = v;
    if (i == 0) offsets[NNODES] = NEDGES;
}

__global__ void scatter_edges(const int* __restrict__ src, const int* __restrict__ dst,
                              int* __restrict__ cursor, int* __restrict__ csr)
{
    int e = blockIdx.x * 256 + threadIdx.x;
    int pos = atomicAdd(&cursor[dst[e]], 1);
    csr[pos] = src[e];
}

// ---------------------------------------------------------------------------
// SAGE max-aggregation: one wave per dst node; y = concat(cf, h) on the fly.
// Empty in-neighborhood -> 0 (matches isfinite-replace in reference).
// ---------------------------------------------------------------------------
__global__ __launch_bounds__(256) void sage_agg(
    const int* __restrict__ offsets, const int* __restrict__ csr,
    const bf16* __restrict__ cf, const bf16* __restrict__ h,
    bf16* __restrict__ agg)
{
    int wid = threadIdx.x >> 6, lane = threadIdx.x & 63;
    int n = blockIdx.x * 4 + wid;
    int beg = offsets[n], end = offsets[n + 1];
    float m0 = -3.4e38f, m1 = m0, m2 = m0, m3 = m0;
    for (int e = beg; e < end; ++e) {
        int s = csr[e];
        m0 = fmaxf(m0, __bfloat162float(cf[(size_t)s * 64 + lane]));
        const bf16* hr = h + (size_t)s * 192;
        m1 = fmaxf(m1, __bfloat162float(hr[lane]));
        m2 = fmaxf(m2, __bfloat162float(hr[64 + lane]));
        m3 = fmaxf(m3, __bfloat162float(hr[128 + lane]));
    }
    if (beg == end) { m0 = m1 = m2 = m3 = 0.f; }
    bf16* ar = agg + (size_t)n * 256;
    ar[lane]       = __float2bfloat16(m0);
    ar[64 + lane]  = __float2bfloat16(m1);
    ar[128 + lane] = __float2bfloat16(m2);
    ar[192 + lane] = __float2bfloat16(m3);
}

// ---------------------------------------------------------------------------
// per-segment sum pool over h [N,192] + fc dot -> scores [512]
// ---------------------------------------------------------------------------
__global__ __launch_bounds__(256) void pool_fc(
    const bf16* __restrict__ h, const int* __restrict__ sep,
    const float* __restrict__ fc_w, float* __restrict__ out)
{
    __shared__ float red[256];
    int b = blockIdx.x, t = threadIdx.x;
    int r0 = (b == 0) ? 0 : sep[b - 1];
    int r1 = sep[b];
    float s0 = 0.f, s1 = 0.f, s2 = 0.f, s3 = 0.f;
    if (t < 192) {
        int r = r0;
        for (; r + 3 < r1; r += 4) {
            s0 += __bfloat162float(h[(size_t)r * 192 + t]);
            s1 += __bfloat162float(h[(size_t)(r + 1) * 192 + t]);
            s2 += __bfloat162float(h[(size_t)(r + 2) * 192 + t]);
            s3 += __bfloat162float(h[(size_t)(r + 3) * 192 + t]);
        }
        for (; r < r1; ++r) s0 += __bfloat162float(h[(size_t)r * 192 + t]);
    }
    red[t] = (t < 192) ? (s0 + s1 + s2 + s3) * fc_w[t] : 0.f;
    __syncthreads();
    #pragma unroll
    for (int st = 128; st > 0; st >>= 1) {
        if (t < st) red[t] += red[t + st];
        __syncthreads();
    }
    if (t == 0) out[b] = red[0];
}

// diagnostic: report ws_size (MiB) through the output if workspace too small
__global__ void report_ws(float* __restrict__ out, float mb)
{
    out[blockIdx.x * 256 + threadIdx.x] = mb;
}

// ---------------------------------------------------------------------------
extern "C" void kernel_launch(void* const* d_in, const int* in_sizes, int n_in,
                              void* d_out, int out_size, void* d_ws, size_t ws_size,
                              hipStream_t stream)
{
    const float* node_features = (const float*)d_in[0];
    const float* node_config   = (const float*)d_in[1];
    const int*   node_sep      = (const int*)d_in[2];
    const int*   node_ops      = (const int*)d_in[3];
    const int*   edges         = (const int*)d_in[4];
    // d_in[5] = batches (unused by the reference math)
    const float* emb    = (const float*)d_in[6];
    const float* nf_w1  = (const float*)d_in[7];
    const float* nf_b1  = (const float*)d_in[8];
    const float* nf_w2  = (const float*)d_in[9];
    const float* nf_b2  = (const float*)d_in[10];
    const float* cf_w1  = (const float*)d_in[11];
    const float* cf_b1  = (const float*)d_in[12];
    const float* cf_w2  = (const float*)d_in[13];
    const float* cf_b2  = (const float*)d_in[14];
    const float* pre_w1 = (const float*)d_in[15];
    const float* pre_b1 = (const float*)d_in[16];
    const float* pre_w2 = (const float*)d_in[17];
    const float* pre_b2 = (const float*)d_in[18];
    const float* sage_wl= (const float*)d_in[19];
    const float* sage_bl= (const float*)d_in[20];
    const float* sage_wr= (const float*)d_in[21];
    const float* mlp_w1 = (const float*)d_in[22];
    const float* mlp_b1 = (const float*)d_in[23];
    const float* mlp_w2 = (const float*)d_in[24];
    const float* mlp_b2 = (const float*)d_in[25];
    const float* fc_w   = (const float*)d_in[26];

    const size_t N = NNODES;

    // Wt blob offsets (elements); total 584,960 bf16
    const size_t WT_NF1  = 0;                          // [176][176]
    const size_t WT_NF2  = WT_NF1  + 176 * 176;        // [192][176]
    const size_t WT_PRE1 = WT_NF2  + 192 * 176;        // [192][256]
    const size_t WT_PRE2 = WT_PRE1 + 192 * 256;        // [192][192]
    const size_t WT_SAGE = WT_PRE2 + 192 * 192;        // 2x [256][512]
    const size_t WT_MLP1 = WT_SAGE + 2 * 256 * 512;    // 2x [192][256]
    const size_t WT_MLP2 = WT_MLP1 + 2 * 192 * 256;    // 2x [192][192]
    const size_t WT_TOT  = WT_MLP2 + 2 * 192 * 192;

    // workspace: bf16 activations | Wt bf16 | CSR ints  (~391 MiB)
    const size_t fl_bytes  = N * 768 * sizeof(bf16);
    const size_t wt_bytes  = WT_TOT * 2;
    const size_t int_elems = (N + 1) + N + N + NEDGES + 256;
    const size_t needed    = fl_bytes + wt_bytes + int_elems * 4;
    if (ws_size < needed) {
        report_ws<<<2, 256, 0, stream>>>((float*)d_out,
                                         (float)((double)ws_size / 1048576.0));
        return;
    }

    bf16* cf   = (bf16*)d_ws;                   // [N,64]
    bf16* h    = cf   + N * 64;                 // [N,192]
    bf16* bufA = h    + N * 192;                // [N,256]  t1/t2/agg
    bf16* bufB = bufA + N * 256;                // [N,256]  x/z
    short* wt  = (short*)(bufB + N * 256);      // Wt blobs (1.14 MB, 16B-aligned)
    int* offsets = (int*)(wt + WT_TOT);         // [N+1]
    int* indeg   = offsets + (N + 1);           // [N]
    int* cursor  = indeg + N;                   // [N]
    int* csr     = cursor + N;                  // [E]
    int* bsums   = csr + NEDGES;                // [256]

    const int* esrc = edges;            // edges[0, :]
    const int* edst = edges + NEDGES;   // edges[1, :]

    dim3 blk(256);
    const int GB = NNODES / 128;        // 2048 gemm blocks

    // ---- weight prep (transpose + bf16) ----
    prep_wt<<<dim3(1, 176), blk, 0, stream>>>(nf_w1, 176, nullptr, wt + WT_NF1, 176, 176);
    prep_wt<<<dim3(1, 192), blk, 0, stream>>>(nf_w2, 176, nullptr, wt + WT_NF2, 176, 192);
    prep_wt<<<dim3(1, 192), blk, 0, stream>>>(pre_w1, 256, nullptr, wt + WT_PRE1, 256, 192);
    prep_wt<<<dim3(1, 192), blk, 0, stream>>>(pre_w2, 192, nullptr, wt + WT_PRE2, 192, 192);
    for (int l = 0; l < 2; ++l) {
        prep_wt<<<dim3(2, 256), blk, 0, stream>>>(
            sage_wl + (size_t)l * 256 * 256, 256, sage_wr + (size_t)l * 256 * 256,
            wt + WT_SAGE + (size_t)l * 256 * 512, 512, 256);
        prep_wt<<<dim3(1, 192), blk, 0, stream>>>(
            mlp_w1 + (size_t)l * 256 * 192, 256, nullptr,
            wt + WT_MLP1 + (size_t)l * 192 * 256, 256, 192);
        prep_wt<<<dim3(1, 192), blk, 0, stream>>>(
            mlp_w2 + (size_t)l * 192 * 192, 192, nullptr,
            wt + WT_MLP2 + (size_t)l * 192 * 192, 192, 192);
    }

    // ---- config-feature MLP -> cf [N,64] ----
    cf_mlp<<<NNODES / 256, blk, 0, stream>>>(node_config, cf_w1, cf_b1, cf_w2, cf_b2, cf);

    // ---- node-feature MLP ----
    mfma_gemm<float, 192><<<GB, blk, 0, stream>>>(
        node_features, 112, emb, 64, (const float*)nullptr, 0, node_ops,
        wt + WT_NF1, nf_b1, nullptr, bufA, 176, 176, 0.01f);
    mfma_gemm<bf16, 192><<<GB, blk, 0, stream>>>(
        bufA, 176, (const bf16*)nullptr, 0, (const bf16*)nullptr, 0, nullptr,
        wt + WT_NF2, nf_b2, nullptr, bufB, 176, 192, 0.01f);

    // ---- prenet ----
    mfma_gemm<bf16, 192><<<GB, blk, 0, stream>>>(
        cf, 64, bufB, 192, (const bf16*)nullptr, 0, nullptr,
        wt + WT_PRE1, pre_b1, nullptr, bufA, 256, 192, 0.2f);
    mfma_gemm<bf16, 192><<<GB, blk, 0, stream>>>(
        bufA, 192, (const bf16*)nullptr, 0, (const bf16*)nullptr, 0, nullptr,
        wt + WT_PRE2, pre_b2, nullptr, h, 192, 192, 0.2f);

    // ---- CSR build ----
    zero_ints<<<NNODES / 256, blk, 0, stream>>>(indeg, NNODES);
    count_deg<<<NEDGES / 256, blk, 0, stream>>>(edst, indeg);
    scan_block<<<NNODES / 1024, blk, 0, stream>>>(indeg, offsets, bsums);
    scan_tops<<<1, blk, 0, stream>>>(bsums);
    scan_fix<<<NNODES / 256, blk, 0, stream>>>(offsets, bsums, cursor);
    scatter_edges<<<NEDGES / 256, blk, 0, stream>>>(esrc, edst, cursor, csr);

    // ---- 2 x (SAGE-max + MLP + residual) ----
    for (int l = 0; l < 2; ++l) {
        sage_agg<<<NNODES / 4, blk, 0, stream>>>(offsets, csr, cf, h, bufA);
        // z = [agg | cf | h] @ [Wl;Wr] + bl   (K=512, identity act)
        mfma_gemm<bf16, 256><<<GB, blk, 0, stream>>>(
            bufA, 256, cf, 64, h, 192, nullptr,
            wt + WT_SAGE + (size_t)l * 256 * 512, sage_bl + (size_t)l * 256,
            nullptr, bufB, 512, 256, 1.0f);
        mfma_gemm<bf16, 192><<<GB, blk, 0, stream>>>(
            bufB, 256, (const bf16*)nullptr, 0, (const bf16*)nullptr, 0, nullptr,
            wt + WT_MLP1 + (size_t)l * 192 * 256, mlp_b1 + (size_t)l * 192,
            nullptr, bufA, 256, 192, 0.2f);
        mfma_gemm<bf16, 192><<<GB, blk, 0, stream>>>(
            bufA, 192, (const bf16*)nullptr, 0, (const bf16*)nullptr, 0, nullptr,
            wt + WT_MLP2 + (size_t)l * 192 * 192, mlp_b2 + (size_t)l * 192,
            h, h, 192, 192, 0.2f);
    }

    // ---- pooled segment sums + fc -> scores [512] ----
    pool_fc<<<NSEG, blk, 0, stream>>>(h, node_sep, fc_w, (float*)d_out);
}

// Round 7
// 1563.503 us; speedup vs baseline: 8.1734x; 1.4342x over previous
//
#include <hip/hip_runtime.h>
#include <hip/hip_bf16.h>
#include <math.h>

#define NNODES 262144
#define NEDGES 524288
#define NSEG   512      // B*C segments

typedef __hip_bfloat16 bf16;
typedef __attribute__((ext_vector_type(8))) short short8;   // 8 bf16 = 4 VGPR
typedef __attribute__((ext_vector_type(4))) short short4v;  // 4 bf16 = 2 VGPR
typedef __attribute__((ext_vector_type(4))) float f32x4;

__device__ __forceinline__ short bfbits(float f) {
    return __builtin_bit_cast(short, (__bf16)f);
}
__device__ __forceinline__ float bitsf(short s) {
    unsigned u = ((unsigned)(unsigned short)s) << 16;
    return __builtin_bit_cast(float, u);
}

// load 8 contiguous virtual-K elements as bf16 bits (16B-aligned: all widths %8==0)
__device__ __forceinline__ short8 ld8(const bf16* p, size_t off) {
    return *(const short8*)((const short*)p + off);
}
__device__ __forceinline__ short8 ld8(const float* p, size_t off) {
    const float4* q = (const float4*)(p + off);
    float4 a = q[0], b = q[1];
    short8 r;
    r[0] = bfbits(a.x); r[1] = bfbits(a.y); r[2] = bfbits(a.z); r[3] = bfbits(a.w);
    r[4] = bfbits(b.x); r[5] = bfbits(b.y); r[6] = bfbits(b.z); r[7] = bfbits(b.w);
    return r;
}

// ---------------------------------------------------------------------------
// Weight prep: Wt[OUT][K] bf16  <-  row-stack{Wa[0:kw), Wb[kw:K)} [K][OUT] fp32
// grid: (ceil(K/256), OUT)
// ---------------------------------------------------------------------------
__global__ void prep_wt(const float* __restrict__ Wa, int kw,
                        const float* __restrict__ Wb,
                        short* __restrict__ Wt, int K, int OUT)
{
    int k = blockIdx.x * 256 + threadIdx.x;
    int c = blockIdx.y;
    if (k < K) {
        float v = (k < kw) ? Wa[(size_t)k * OUT + c] : Wb[(size_t)(k - kw) * OUT + c];
        Wt[(size_t)c * K + k] = bfbits(v);
    }
}

// ---------------------------------------------------------------------------
// MFMA GEMM v2: out[n,:OUT] = res + lrelu_alpha( A[n,:K] @ W + bias ), W = Wt^T
// 512 threads (8 waves, 2x4), tile 128 rows x BN cols, BK=32.
// Wave sub-tile 64 x BN/4 -> acc[BN/64][4] (<=64 VGPR). launch_bounds(512,4)
// caps VGPR at 128 -> 4 waves/SIMD.
// SWAPPED mfma operands: mfma(b_frag, a_frag) yields D^T layout, so each lane
// holds 4 CONSECUTIVE output cols of one row -> 8B ushort4 stores (coalesced).
// ---------------------------------------------------------------------------
template<typename TA, int BN>
__global__ __launch_bounds__(512, 4) void mfma_gemm(
    const TA* __restrict__ A0, int w0,
    const TA* __restrict__ A1, int w1,
    const TA* __restrict__ A2, int w2,
    const int*   __restrict__ gidx,
    const short* __restrict__ Wt,
    const float* __restrict__ bias,
    const bf16*  __restrict__ res,
    bf16* __restrict__ out,
    int K, int OUT, float alpha)
{
    constexpr int NRW = BN / 64;        // n-frags per wave (wave covers BN/4)
    __shared__ short As[128 * 40];
    __shared__ short Bs[BN * 40];
    __shared__ float biasLds[BN];

    const int tid  = threadIdx.x;
    const int lane = tid & 63;
    const int wid  = tid >> 6;          // 0..7
    const int row0 = blockIdx.x * 128;
    const int wr   = (wid >> 2) * 64;       // wave row offset (0,64)
    const int wc   = (wid & 3) * (BN / 4);  // wave col offset
    const int fr   = lane & 15;
    const int fc   = lane >> 4;

    if (tid < BN) biasLds[tid] = (tid < OUT) ? bias[tid] : 0.f;

    f32x4 acc[NRW][4];
    #pragma unroll
    for (int nr = 0; nr < NRW; ++nr)
        #pragma unroll
        for (int m = 0; m < 4; ++m) acc[nr][m] = f32x4{0.f, 0.f, 0.f, 0.f};

    for (int k0 = 0; k0 < K; k0 += 32) {
        // ---- stage A tile: 128 rows x 32 k, exactly 1 chunk/thread ----
        {
            int r  = tid >> 2;
            int kl = (tid & 3) * 8;
            int gk = k0 + kl;
            short8 v{};
            if (gk < K) {
                int n = row0 + r;
                if (gk < w0) v = ld8(A0, (size_t)n * w0 + gk);
                else {
                    int k1 = gk - w0;
                    if (k1 < w1) {
                        int rr = gidx ? gidx[n] : n;
                        v = ld8(A1, (size_t)rr * w1 + k1);
                    } else {
                        v = ld8(A2, (size_t)n * w2 + (k1 - w1));
                    }
                }
            }
            *(short8*)&As[r * 40 + kl] = v;
        }
        // ---- stage B tile: BN cols x 32 k from Wt[OUT][K] ----
        #pragma unroll
        for (int i = 0; i < (BN * 4 + 511) / 512; ++i) {
            int f = i * 512 + tid;
            if (f < BN * 4) {
                int c  = f >> 2;
                int kl = (f & 3) * 8;
                int gk = k0 + kl;
                short8 v{};
                if (gk < K && c < OUT) v = *(const short8*)&Wt[(size_t)c * K + gk];
                *(short8*)&Bs[c * 40 + kl] = v;
            }
        }
        __syncthreads();
        // ---- compute: 4 A-frags, NRW B-frags, 4*NRW mfma (swapped args) ----
        short8 af[4];
        #pragma unroll
        for (int m = 0; m < 4; ++m)
            af[m] = *(short8*)&As[(wr + m * 16 + fr) * 40 + fc * 8];
        #pragma unroll
        for (int nr = 0; nr < NRW; ++nr) {
            short8 bfr = *(short8*)&Bs[(wc + nr * 16 + fr) * 40 + fc * 8];
            #pragma unroll
            for (int m = 0; m < 4; ++m)
                acc[nr][m] = __builtin_amdgcn_mfma_f32_16x16x32_bf16(
                    bfr, af[m], acc[nr][m], 0, 0, 0);
        }
        __syncthreads();
    }
    // ---- epilogue: D^T layout -> lane holds row (row0+wr+m*16+fr),
    //      cols c0..c0+3 with c0 = wc+nr*16+fc*4. One 8B store per frag. ----
    #pragma unroll
    for (int nr = 0; nr < NRW; ++nr) {
        int c0 = wc + nr * 16 + fc * 4;
        if (c0 < OUT) {
            #pragma unroll
            for (int m = 0; m < 4; ++m) {
                int r = row0 + wr + m * 16 + fr;
                size_t base = (size_t)r * OUT + c0;
                short4v o;
                if (res) {
                    short4v rv = *(const short4v*)((const short*)res + base);
                    #pragma unroll
                    for (int j = 0; j < 4; ++j) {
                        float v = acc[nr][m][j] + biasLds[c0 + j];
                        v = (v > 0.f) ? v : alpha * v;
                        o[j] = bfbits(v + bitsf(rv[j]));
                    }
                } else {
                    #pragma unroll
                    for (int j = 0; j < 4; ++j) {
                        float v = acc[nr][m][j] + biasLds[c0 + j];
                        v = (v > 0.f) ? v : alpha * v;
                        o[j] = bfbits(v);
                    }
                }
                *(short4v*)((short*)out + base) = o;
            }
        }
    }
}

// ---------------------------------------------------------------------------
// config-feature MLP: 14 -> 14 (lrelu .01) -> 64 (lrelu .01), one thread/node
// ---------------------------------------------------------------------------
__global__ __launch_bounds__(256) void cf_mlp(
    const float* __restrict__ ncf,
    const float* __restrict__ w1, const float* __restrict__ b1,
    const float* __restrict__ w2, const float* __restrict__ b2,
    bf16* __restrict__ cf)
{
    __shared__ float W1s[196], B1s[14], W2s[896], B2s[64];
    int t = threadIdx.x;
    for (int i = t; i < 196; i += 256) W1s[i] = w1[i];
    for (int i = t; i < 896; i += 256) W2s[i] = w2[i];
    if (t < 14) B1s[t] = b1[t];
    if (t >= 32 && t < 96) B2s[t - 32] = b2[t - 32];
    __syncthreads();

    int n = blockIdx.x * 256 + t;
    float in[14], hid[14];
    #pragma unroll
    for (int k = 0; k < 14; ++k) in[k] = ncf[(size_t)n * 14 + k];
    #pragma unroll
    for (int j = 0; j < 14; ++j) {
        float s = B1s[j];
        #pragma unroll
        for (int k = 0; k < 14; ++k) s += in[k] * W1s[k * 14 + j];
        hid[j] = (s > 0.f) ? s : 0.01f * s;
    }
    #pragma unroll 4
    for (int j = 0; j < 64; ++j) {
        float s = B2s[j];
        #pragma unroll
        for (int k = 0; k < 14; ++k) s += hid[k] * W2s[k * 64 + j];
        s = (s > 0.f) ? s : 0.01f * s;
        cf[(size_t)n * 64 + j] = __float2bfloat16(s);
    }
}

// ---------------------------------------------------------------------------
// CSR build: zero -> indeg count -> 3-phase exclusive scan -> scatter
// ---------------------------------------------------------------------------
__global__ void zero_ints(int* __restrict__ p, int n)
{
    int i = blockIdx.x * 256 + threadIdx.x;
    if (i < n) p[i] = 0;
}

__global__ void count_deg(const int* __restrict__ dst, int* __restrict__ indeg)
{
    int e = blockIdx.x * 256 + threadIdx.x;
    atomicAdd(&indeg[dst[e]], 1);
}

__global__ __launch_bounds__(256) void scan_block(
    const int* __restrict__ in, int* __restrict__ part, int* __restrict__ bsums)
{
    __shared__ int sh[256];
    int t = threadIdx.x, b = blockIdx.x;
    int base = b * 1024 + t * 4;
    int v0 = in[base], v1 = in[base + 1], v2 = in[base + 2], v3 = in[base + 3];
    int s = v0 + v1 + v2 + v3;
    sh[t] = s; __syncthreads();
    #pragma unroll
    for (int off = 1; off < 256; off <<= 1) {
        int x = (t >= off) ? sh[t - off] : 0;
        __syncthreads();
        sh[t] += x;
        __syncthreads();
    }
    int excl = sh[t] - s;
    if (t == 255) bsums[b] = sh[t];
    part[base]     = excl;
    part[base + 1] = excl + v0;
    part[base + 2] = excl + v0 + v1;
    part[base + 3] = excl + v0 + v1 + v2;
}

__global__ __launch_bounds__(256) void scan_tops(int* __restrict__ bsums)
{
    __shared__ int sh[256];
    int t = threadIdx.x;
    int s = bsums[t];
    sh[t] = s; __syncthreads();
    #pragma unroll
    for (int off = 1; off < 256; off <<= 1) {
        int x = (t >= off) ? sh[t - off] : 0;
        __syncthreads();
        sh[t] += x;
        __syncthreads();
    }
    bsums[t] = sh[t] - s;   // exclusive
}

__global__ void scan_fix(int* __restrict__ offsets, const int* __restrict__ bsums,
                         int* __restrict__ cursor)
{
    int i = blockIdx.x * 256 + threadIdx.x;
    int v = offsets[i] + bsums[i >> 10];
    offsets[i] = v;
    cursor[i]  = v;
    if (i == 0) offsets[NNODES] = NEDGES;
}

__global__ void scatter_edges(const int* __restrict__ src, const int* __restrict__ dst,
                              int* __restrict__ cursor, int* __restrict__ csr)
{
    int e = blockIdx.x * 256 + threadIdx.x;
    int pos = atomicAdd(&cursor[dst[e]], 1);
    csr[pos] = src[e];
}

// ---------------------------------------------------------------------------
// SAGE max-aggregation: one wave per dst node; y = concat(cf, h) on the fly.
// Empty in-neighborhood -> 0 (matches isfinite-replace in reference).
// ---------------------------------------------------------------------------
__global__ __launch_bounds__(256) void sage_agg(
    const int* __restrict__ offsets, const int* __restrict__ csr,
    const bf16* __restrict__ cf, const bf16* __restrict__ h,
    bf16* __restrict__ agg)
{
    int wid = threadIdx.x >> 6, lane = threadIdx.x & 63;
    int n = blockIdx.x * 4 + wid;
    int beg = offsets[n], end = offsets[n + 1];
    float m0 = -3.4e38f, m1 = m0, m2 = m0, m3 = m0;
    for (int e = beg; e < end; ++e) {
        int s = csr[e];
        m0 = fmaxf(m0, __bfloat162float(cf[(size_t)s * 64 + lane]));
        const bf16* hr = h + (size_t)s * 192;
        m1 = fmaxf(m1, __bfloat162float(hr[lane]));
        m2 = fmaxf(m2, __bfloat162float(hr[64 + lane]));
        m3 = fmaxf(m3, __bfloat162float(hr[128 + lane]));
    }
    if (beg == end) { m0 = m1 = m2 = m3 = 0.f; }
    bf16* ar = agg + (size_t)n * 256;
    ar[lane]       = __float2bfloat16(m0);
    ar[64 + lane]  = __float2bfloat16(m1);
    ar[128 + lane] = __float2bfloat16(m2);
    ar[192 + lane] = __float2bfloat16(m3);
}

// ---------------------------------------------------------------------------
// per-segment sum pool over h [N,192] + fc dot -> scores [512]
// ---------------------------------------------------------------------------
__global__ __launch_bounds__(256) void pool_fc(
    const bf16* __restrict__ h, const int* __restrict__ sep,
    const float* __restrict__ fc_w, float* __restrict__ out)
{
    __shared__ float red[256];
    int b = blockIdx.x, t = threadIdx.x;
    int r0 = (b == 0) ? 0 : sep[b - 1];
    int r1 = sep[b];
    float s0 = 0.f, s1 = 0.f, s2 = 0.f, s3 = 0.f;
    if (t < 192) {
        int r = r0;
        for (; r + 3 < r1; r += 4) {
            s0 += __bfloat162float(h[(size_t)r * 192 + t]);
            s1 += __bfloat162float(h[(size_t)(r + 1) * 192 + t]);
            s2 += __bfloat162float(h[(size_t)(r + 2) * 192 + t]);
            s3 += __bfloat162float(h[(size_t)(r + 3) * 192 + t]);
        }
        for (; r < r1; ++r) s0 += __bfloat162float(h[(size_t)r * 192 + t]);
    }
    red[t] = (t < 192) ? (s0 + s1 + s2 + s3) * fc_w[t] : 0.f;
    __syncthreads();
    #pragma unroll
    for (int st = 128; st > 0; st >>= 1) {
        if (t < st) red[t] += red[t + st];
        __syncthreads();
    }
    if (t == 0) out[b] = red[0];
}

// diagnostic: report ws_size (MiB) through the output if workspace too small
__global__ void report_ws(float* __restrict__ out, float mb)
{
    out[blockIdx.x * 256 + threadIdx.x] = mb;
}

// ---------------------------------------------------------------------------
extern "C" void kernel_launch(void* const* d_in, const int* in_sizes, int n_in,
                              void* d_out, int out_size, void* d_ws, size_t ws_size,
                              hipStream_t stream)
{
    const float* node_features = (const float*)d_in[0];
    const float* node_config   = (const float*)d_in[1];
    const int*   node_sep      = (const int*)d_in[2];
    const int*   node_ops      = (const int*)d_in[3];
    const int*   edges         = (const int*)d_in[4];
    // d_in[5] = batches (unused by the reference math)
    const float* emb    = (const float*)d_in[6];
    const float* nf_w1  = (const float*)d_in[7];
    const float* nf_b1  = (const float*)d_in[8];
    const float* nf_w2  = (const float*)d_in[9];
    const float* nf_b2  = (const float*)d_in[10];
    const float* cf_w1  = (const float*)d_in[11];
    const float* cf_b1  = (const float*)d_in[12];
    const float* cf_w2  = (const float*)d_in[13];
    const float* cf_b2  = (const float*)d_in[14];
    const float* pre_w1 = (const float*)d_in[15];
    const float* pre_b1 = (const float*)d_in[16];
    const float* pre_w2 = (const float*)d_in[17];
    const float* pre_b2 = (const float*)d_in[18];
    const float* sage_wl= (const float*)d_in[19];
    const float* sage_bl= (const float*)d_in[20];
    const float* sage_wr= (const float*)d_in[21];
    const float* mlp_w1 = (const float*)d_in[22];
    const float* mlp_b1 = (const float*)d_in[23];
    const float* mlp_w2 = (const float*)d_in[24];
    const float* mlp_b2 = (const float*)d_in[25];
    const float* fc_w   = (const float*)d_in[26];

    const size_t N = NNODES;

    // Wt blob offsets (elements); total 584,960 bf16
    const size_t WT_NF1  = 0;                          // [176][176]
    const size_t WT_NF2  = WT_NF1  + 176 * 176;        // [192][176]
    const size_t WT_PRE1 = WT_NF2  + 192 * 176;        // [192][256]
    const size_t WT_PRE2 = WT_PRE1 + 192 * 256;        // [192][192]
    const size_t WT_SAGE = WT_PRE2 + 192 * 192;        // 2x [256][512]
    const size_t WT_MLP1 = WT_SAGE + 2 * 256 * 512;    // 2x [192][256]
    const size_t WT_MLP2 = WT_MLP1 + 2 * 192 * 256;    // 2x [192][192]
    const size_t WT_TOT  = WT_MLP2 + 2 * 192 * 192;

    // workspace: bf16 activations | Wt bf16 | CSR ints  (~391 MiB)
    const size_t fl_bytes  = N * 768 * sizeof(bf16);
    const size_t wt_bytes  = WT_TOT * 2;
    const size_t int_elems = (N + 1) + N + N + NEDGES + 256;
    const size_t needed    = fl_bytes + wt_bytes + int_elems * 4;
    if (ws_size < needed) {
        report_ws<<<2, 256, 0, stream>>>((float*)d_out,
                                         (float)((double)ws_size / 1048576.0));
        return;
    }

    bf16* cf   = (bf16*)d_ws;                   // [N,64]
    bf16* h    = cf   + N * 64;                 // [N,192]
    bf16* bufA = h    + N * 192;                // [N,256]  t1/t2/agg
    bf16* bufB = bufA + N * 256;                // [N,256]  x/z
    short* wt  = (short*)(bufB + N * 256);      // Wt blobs (1.14 MB, 16B-aligned)
    int* offsets = (int*)(wt + WT_TOT);         // [N+1]
    int* indeg   = offsets + (N + 1);           // [N]
    int* cursor  = indeg + N;                   // [N]
    int* csr     = cursor + N;                  // [E]
    int* bsums   = csr + NEDGES;                // [256]

    const int* esrc = edges;            // edges[0, :]
    const int* edst = edges + NEDGES;   // edges[1, :]

    dim3 blk(256);
    dim3 blk512(512);
    const int GB = NNODES / 128;        // 2048 gemm blocks

    // ---- weight prep (transpose + bf16) ----
    prep_wt<<<dim3(1, 176), blk, 0, stream>>>(nf_w1, 176, nullptr, wt + WT_NF1, 176, 176);
    prep_wt<<<dim3(1, 192), blk, 0, stream>>>(nf_w2, 176, nullptr, wt + WT_NF2, 176, 192);
    prep_wt<<<dim3(1, 192), blk, 0, stream>>>(pre_w1, 256, nullptr, wt + WT_PRE1, 256, 192);
    prep_wt<<<dim3(1, 192), blk, 0, stream>>>(pre_w2, 192, nullptr, wt + WT_PRE2, 192, 192);
    for (int l = 0; l < 2; ++l) {
        prep_wt<<<dim3(2, 256), blk, 0, stream>>>(
            sage_wl + (size_t)l * 256 * 256, 256, sage_wr + (size_t)l * 256 * 256,
            wt + WT_SAGE + (size_t)l * 256 * 512, 512, 256);
        prep_wt<<<dim3(1, 192), blk, 0, stream>>>(
            mlp_w1 + (size_t)l * 256 * 192, 256, nullptr,
            wt + WT_MLP1 + (size_t)l * 192 * 256, 256, 192);
        prep_wt<<<dim3(1, 192), blk, 0, stream>>>(
            mlp_w2 + (size_t)l * 192 * 192, 192, nullptr,
            wt + WT_MLP2 + (size_t)l * 192 * 192, 192, 192);
    }

    // ---- config-feature MLP -> cf [N,64] ----
    cf_mlp<<<NNODES / 256, blk, 0, stream>>>(node_config, cf_w1, cf_b1, cf_w2, cf_b2, cf);

    // ---- node-feature MLP ----
    mfma_gemm<float, 192><<<GB, blk512, 0, stream>>>(
        node_features, 112, emb, 64, (const float*)nullptr, 0, node_ops,
        wt + WT_NF1, nf_b1, nullptr, bufA, 176, 176, 0.01f);
    mfma_gemm<bf16, 192><<<GB, blk512, 0, stream>>>(
        bufA, 176, (const bf16*)nullptr, 0, (const bf16*)nullptr, 0, nullptr,
        wt + WT_NF2, nf_b2, nullptr, bufB, 176, 192, 0.01f);

    // ---- prenet ----
    mfma_gemm<bf16, 192><<<GB, blk512, 0, stream>>>(
        cf, 64, bufB, 192, (const bf16*)nullptr, 0, nullptr,
        wt + WT_PRE1, pre_b1, nullptr, bufA, 256, 192, 0.2f);
    mfma_gemm<bf16, 192><<<GB, blk512, 0, stream>>>(
        bufA, 192, (const bf16*)nullptr, 0, (const bf16*)nullptr, 0, nullptr,
        wt + WT_PRE2, pre_b2, nullptr, h, 192, 192, 0.2f);

    // ---- CSR build ----
    zero_ints<<<NNODES / 256, blk, 0, stream>>>(indeg, NNODES);
    count_deg<<<NEDGES / 256, blk, 0, stream>>>(edst, indeg);
    scan_block<<<NNODES / 1024, blk, 0, stream>>>(indeg, offsets, bsums);
    scan_tops<<<1, blk, 0, stream>>>(bsums);
    scan_fix<<<NNODES / 256, blk, 0, stream>>>(offsets, bsums, cursor);
    scatter_edges<<<NEDGES / 256, blk, 0, stream>>>(esrc, edst, cursor, csr);

    // ---- 2 x (SAGE-max + MLP + residual) ----
    for (int l = 0; l < 2; ++l) {
        sage_agg<<<NNODES / 4, blk, 0, stream>>>(offsets, csr, cf, h, bufA);
        // z = [agg | cf | h] @ [Wl;Wr] + bl   (K=512, identity act)
        mfma_gemm<bf16, 256><<<GB, blk512, 0, stream>>>(
            bufA, 256, cf, 64, h, 192, nullptr,
            wt + WT_SAGE + (size_t)l * 256 * 512, sage_bl + (size_t)l * 256,
            nullptr, bufB, 512, 256, 1.0f);
        mfma_gemm<bf16, 192><<<GB, blk512, 0, stream>>>(
            bufB, 256, (const bf16*)nullptr, 0, (const bf16*)nullptr, 0, nullptr,
            wt + WT_MLP1 + (size_t)l * 192 * 256, mlp_b1 + (size_t)l * 192,
            nullptr, bufA, 256, 192, 0.2f);
        mfma_gemm<bf16, 192><<<GB, blk512, 0, stream>>>(
            bufA, 192, (const bf16*)nullptr, 0, (const bf16*)nullptr, 0, nullptr,
            wt + WT_MLP2 + (size_t)l * 192 * 192, mlp_b2 + (size_t)l * 192,
            h, h, 192, 192, 0.2f);
    }

    // ---- pooled segment sums + fc -> scores [512] ----
    pool_fc<<<NSEG, blk, 0, stream>>>(h, node_sep, fc_w, (float*)d_out);
}

// Round 8
// 1396.570 us; speedup vs baseline: 9.1504x; 1.1195x over previous
//
#include <hip/hip_runtime.h>
#include <hip/hip_bf16.h>
#include <math.h>

#define NNODES 262144
#define NEDGES 524288
#define NSEG   512      // B*C segments

typedef __hip_bfloat16 bf16;
typedef __attribute__((ext_vector_type(8))) short short8;   // 8 bf16 = 4 VGPR
typedef __attribute__((ext_vector_type(4))) short short4v;  // 4 bf16 = 2 VGPR
typedef __attribute__((ext_vector_type(4))) float f32x4;

__device__ __forceinline__ short bfbits(float f) {
    return __builtin_bit_cast(short, (__bf16)f);
}
__device__ __forceinline__ float bitsf(short s) {
    unsigned u = ((unsigned)(unsigned short)s) << 16;
    return __builtin_bit_cast(float, u);
}

// load 8 contiguous virtual-K elements as bf16 bits (16B-aligned: all widths %8==0)
__device__ __forceinline__ short8 ld8(const bf16* p, size_t off) {
    return *(const short8*)((const short*)p + off);
}
__device__ __forceinline__ short8 ld8(const float* p, size_t off) {
    const float4* q = (const float4*)(p + off);
    float4 a = q[0], b = q[1];
    short8 r;
    r[0] = bfbits(a.x); r[1] = bfbits(a.y); r[2] = bfbits(a.z); r[3] = bfbits(a.w);
    r[4] = bfbits(b.x); r[5] = bfbits(b.y); r[6] = bfbits(b.z); r[7] = bfbits(b.w);
    return r;
}

// ---------------------------------------------------------------------------
// Fused weight prep: one launch transposes all 10 matrices to Wt[OUT][K] bf16.
// grid (2, 256, 10): blockIdx.x = k-chunk, .y = out col, .z = job.
// ---------------------------------------------------------------------------
struct PrepJobs {
    const float* wa[10];
    const float* wb[10];
    int kw[10]; int K[10]; int OUT[10]; long off[10];
};

__global__ void prep_all(PrepJobs jobs, short* __restrict__ wt)
{
    int j = blockIdx.z;
    int k = blockIdx.x * 256 + threadIdx.x;
    int c = blockIdx.y;
    int K = jobs.K[j], OUT = jobs.OUT[j];
    if (k < K && c < OUT) {
        int kw = jobs.kw[j];
        float v = (k < kw) ? jobs.wa[j][(size_t)k * OUT + c]
                           : jobs.wb[j][(size_t)(k - kw) * OUT + c];
        wt[jobs.off[j] + (size_t)c * K + k] = bfbits(v);
    }
}

// ---------------------------------------------------------------------------
// MFMA GEMM v3: out[n,:OUT] = res + lrelu_alpha( A[n,:K] @ W + bias ), W = Wt^T
// 512 threads (8 waves, 2x4), tile 128 rows x BN cols, BK=32.
// 2-phase pipeline (T14): issue K-step t+1's global loads right after the
// stage barrier so they overlap the MFMA of step t; LDS write happens next
// iteration. Wave sub-tile 64 x BN/4 -> acc[BN/64][4]. launch_bounds(512,4).
// SWAPPED mfma operands: mfma(b_frag, a_frag) yields D^T layout -> each lane
// holds 4 consecutive output cols of one row -> 8B stores.
// ---------------------------------------------------------------------------
template<typename TA, int BN>
__global__ __launch_bounds__(512, 4) void mfma_gemm(
    const TA* __restrict__ A0, int w0,
    const TA* __restrict__ A1, int w1,
    const TA* __restrict__ A2, int w2,
    const int*   __restrict__ gidx,
    const short* __restrict__ Wt,
    const float* __restrict__ bias,
    const bf16*  __restrict__ res,
    bf16* __restrict__ out,
    int K, int OUT, float alpha)
{
    constexpr int NRW = BN / 64;              // n-frags per wave
    constexpr int NB  = (BN * 4 + 511) / 512; // B chunks per thread
    __shared__ short As[128 * 40];
    __shared__ short Bs[BN * 40];
    __shared__ float biasLds[BN];

    const int tid  = threadIdx.x;
    const int lane = tid & 63;
    const int wid  = tid >> 6;          // 0..7
    const int row0 = blockIdx.x * 128;
    const int wr   = (wid >> 2) * 64;       // wave row offset (0,64)
    const int wc   = (wid & 3) * (BN / 4);  // wave col offset
    const int fr   = lane & 15;
    const int fc   = lane >> 4;

    if (tid < BN) biasLds[tid] = (tid < OUT) ? bias[tid] : 0.f;

    // fixed per-thread staging coordinates
    const int ar  = tid >> 2;           // A row
    const int akl = (tid & 3) * 8;      // A k-offset

    auto loadA = [&](int k0) -> short8 {
        int gk = k0 + akl;
        short8 v{};
        if (gk < K) {
            int n = row0 + ar;
            if (gk < w0) v = ld8(A0, (size_t)n * w0 + gk);
            else {
                int k1 = gk - w0;
                if (k1 < w1) {
                    int rr = gidx ? gidx[n] : n;
                    v = ld8(A1, (size_t)rr * w1 + k1);
                } else {
                    v = ld8(A2, (size_t)n * w2 + (k1 - w1));
                }
            }
        }
        return v;
    };
    auto loadB = [&](int k0, int i) -> short8 {
        int f = i * 512 + tid;
        short8 v{};
        if (f < BN * 4) {
            int c  = f >> 2;
            int gk = k0 + (f & 3) * 8;
            if (gk < K && c < OUT) v = *(const short8*)&Wt[(size_t)c * K + gk];
        }
        return v;
    };

    f32x4 acc[NRW][4];
    #pragma unroll
    for (int nr = 0; nr < NRW; ++nr)
        #pragma unroll
        for (int m = 0; m < 4; ++m) acc[nr][m] = f32x4{0.f, 0.f, 0.f, 0.f};

    // prologue: load K-step 0 into registers
    short8 aC = loadA(0);
    short8 bC[NB];
    #pragma unroll
    for (int i = 0; i < NB; ++i) bC[i] = loadB(0, i);

    for (int k0 = 0; k0 < K; k0 += 32) {
        // ---- write staged registers to LDS ----
        *(short8*)&As[ar * 40 + akl] = aC;
        #pragma unroll
        for (int i = 0; i < NB; ++i) {
            int f = i * 512 + tid;
            if (f < BN * 4) {
                int c  = f >> 2;
                int kl = (f & 3) * 8;
                *(short8*)&Bs[c * 40 + kl] = bC[i];
            }
        }
        __syncthreads();
        // ---- issue next K-step's loads (overlap with MFMA below) ----
        short8 aN{};
        short8 bN[NB];
        #pragma unroll
        for (int i = 0; i < NB; ++i) bN[i] = short8{};
        if (k0 + 32 < K) {
            aN = loadA(k0 + 32);
            #pragma unroll
            for (int i = 0; i < NB; ++i) bN[i] = loadB(k0 + 32, i);
        }
        // ---- compute: 4 A-frags, NRW B-frags, 4*NRW mfma (swapped args) ----
        short8 af[4];
        #pragma unroll
        for (int m = 0; m < 4; ++m)
            af[m] = *(short8*)&As[(wr + m * 16 + fr) * 40 + fc * 8];
        #pragma unroll
        for (int nr = 0; nr < NRW; ++nr) {
            short8 bfr = *(short8*)&Bs[(wc + nr * 16 + fr) * 40 + fc * 8];
            #pragma unroll
            for (int m = 0; m < 4; ++m)
                acc[nr][m] = __builtin_amdgcn_mfma_f32_16x16x32_bf16(
                    bfr, af[m], acc[nr][m], 0, 0, 0);
        }
        __syncthreads();
        aC = aN;
        #pragma unroll
        for (int i = 0; i < NB; ++i) bC[i] = bN[i];
    }
    // ---- epilogue: D^T layout -> lane holds row (row0+wr+m*16+fr),
    //      cols c0..c0+3 with c0 = wc+nr*16+fc*4. One 8B store per frag. ----
    #pragma unroll
    for (int nr = 0; nr < NRW; ++nr) {
        int c0 = wc + nr * 16 + fc * 4;
        if (c0 < OUT) {
            #pragma unroll
            for (int m = 0; m < 4; ++m) {
                int r = row0 + wr + m * 16 + fr;
                size_t base = (size_t)r * OUT + c0;
                short4v o;
                if (res) {
                    short4v rv = *(const short4v*)((const short*)res + base);
                    #pragma unroll
                    for (int j = 0; j < 4; ++j) {
                        float v = acc[nr][m][j] + biasLds[c0 + j];
                        v = (v > 0.f) ? v : alpha * v;
                        o[j] = bfbits(v + bitsf(rv[j]));
                    }
                } else {
                    #pragma unroll
                    for (int j = 0; j < 4; ++j) {
                        float v = acc[nr][m][j] + biasLds[c0 + j];
                        v = (v > 0.f) ? v : alpha * v;
                        o[j] = bfbits(v);
                    }
                }
                *(short4v*)((short*)out + base) = o;
            }
        }
    }
}

// ---------------------------------------------------------------------------
// config-feature MLP: 14 -> 14 (lrelu .01) -> 64 (lrelu .01), one thread/node
// ---------------------------------------------------------------------------
__global__ __launch_bounds__(256) void cf_mlp(
    const float* __restrict__ ncf,
    const float* __restrict__ w1, const float* __restrict__ b1,
    const float* __restrict__ w2, const float* __restrict__ b2,
    bf16* __restrict__ cf)
{
    __shared__ float W1s[196], B1s[14], W2s[896], B2s[64];
    int t = threadIdx.x;
    for (int i = t; i < 196; i += 256) W1s[i] = w1[i];
    for (int i = t; i < 896; i += 256) W2s[i] = w2[i];
    if (t < 14) B1s[t] = b1[t];
    if (t >= 32 && t < 96) B2s[t - 32] = b2[t - 32];
    __syncthreads();

    int n = blockIdx.x * 256 + t;
    float in[14], hid[14];
    #pragma unroll
    for (int k = 0; k < 14; ++k) in[k] = ncf[(size_t)n * 14 + k];
    #pragma unroll
    for (int j = 0; j < 14; ++j) {
        float s = B1s[j];
        #pragma unroll
        for (int k = 0; k < 14; ++k) s += in[k] * W1s[k * 14 + j];
        hid[j] = (s > 0.f) ? s : 0.01f * s;
    }
    #pragma unroll 4
    for (int j = 0; j < 64; ++j) {
        float s = B2s[j];
        #pragma unroll
        for (int k = 0; k < 14; ++k) s += hid[k] * W2s[k * 64 + j];
        s = (s > 0.f) ? s : 0.01f * s;
        cf[(size_t)n * 64 + j] = __float2bfloat16(s);
    }
}

// ---------------------------------------------------------------------------
// CSR build: zero -> indeg count -> 3-phase exclusive scan -> scatter
// ---------------------------------------------------------------------------
__global__ void zero_ints(int* __restrict__ p, int n)
{
    int i = blockIdx.x * 256 + threadIdx.x;
    if (i < n) p[i] = 0;
}

__global__ void count_deg(const int* __restrict__ dst, int* __restrict__ indeg)
{
    int e = blockIdx.x * 256 + threadIdx.x;
    atomicAdd(&indeg[dst[e]], 1);
}

__global__ __launch_bounds__(256) void scan_block(
    const int* __restrict__ in, int* __restrict__ part, int* __restrict__ bsums)
{
    __shared__ int sh[256];
    int t = threadIdx.x, b = blockIdx.x;
    int base = b * 1024 + t * 4;
    int v0 = in[base], v1 = in[base + 1], v2 = in[base + 2], v3 = in[base + 3];
    int s = v0 + v1 + v2 + v3;
    sh[t] = s; __syncthreads();
    #pragma unroll
    for (int off = 1; off < 256; off <<= 1) {
        int x = (t >= off) ? sh[t - off] : 0;
        __syncthreads();
        sh[t] += x;
        __syncthreads();
    }
    int excl = sh[t] - s;
    if (t == 255) bsums[b] = sh[t];
    part[base]     = excl;
    part[base + 1] = excl + v0;
    part[base + 2] = excl + v0 + v1;
    part[base + 3] = excl + v0 + v1 + v2;
}

__global__ __launch_bounds__(256) void scan_tops(int* __restrict__ bsums)
{
    __shared__ int sh[256];
    int t = threadIdx.x;
    int s = bsums[t];
    sh[t] = s; __syncthreads();
    #pragma unroll
    for (int off = 1; off < 256; off <<= 1) {
        int x = (t >= off) ? sh[t - off] : 0;
        __syncthreads();
        sh[t] += x;
        __syncthreads();
    }
    bsums[t] = sh[t] - s;   // exclusive
}

__global__ void scan_fix(int* __restrict__ offsets, const int* __restrict__ bsums,
                         int* __restrict__ cursor)
{
    int i = blockIdx.x * 256 + threadIdx.x;
    int v = offsets[i] + bsums[i >> 10];
    offsets[i] = v;
    cursor[i]  = v;
    if (i == 0) offsets[NNODES] = NEDGES;
}

__global__ void scatter_edges(const int* __restrict__ src, const int* __restrict__ dst,
                              int* __restrict__ cursor, int* __restrict__ csr)
{
    int e = blockIdx.x * 256 + threadIdx.x;
    int pos = atomicAdd(&cursor[dst[e]], 1);
    csr[pos] = src[e];
}

// ---------------------------------------------------------------------------
// SAGE max-aggregation v2: one wave per dst node; lane covers 4 consecutive
// cols of y=[cf(64)|h(192)] -> ONE 8B load per edge per lane (was 4 loads).
// 2-edge unroll to overlap gather latency. Empty neighborhood -> 0.
// ---------------------------------------------------------------------------
__global__ __launch_bounds__(256) void sage_agg(
    const int* __restrict__ offsets, const int* __restrict__ csr,
    const bf16* __restrict__ cf, const bf16* __restrict__ h,
    bf16* __restrict__ agg)
{
    int wid = threadIdx.x >> 6, lane = threadIdx.x & 63;
    int n = blockIdx.x * 4 + wid;
    int beg = offsets[n], end = offsets[n + 1];

    bool isCf = lane < 16;
    const short* basep = isCf ? (const short*)cf : (const short*)h;
    int rowW   = isCf ? 64 : 192;
    int colOff = isCf ? lane * 4 : lane * 4 - 64;

    float m0 = -3.4e38f, m1 = m0, m2 = m0, m3 = m0;
    int e = beg;
    for (; e + 1 < end; e += 2) {
        int s0 = csr[e], s1 = csr[e + 1];
        short4v v0 = *(const short4v*)(basep + (size_t)s0 * rowW + colOff);
        short4v v1 = *(const short4v*)(basep + (size_t)s1 * rowW + colOff);
        m0 = fmaxf(fmaxf(m0, bitsf(v0[0])), bitsf(v1[0]));
        m1 = fmaxf(fmaxf(m1, bitsf(v0[1])), bitsf(v1[1]));
        m2 = fmaxf(fmaxf(m2, bitsf(v0[2])), bitsf(v1[2]));
        m3 = fmaxf(fmaxf(m3, bitsf(v0[3])), bitsf(v1[3]));
    }
    if (e < end) {
        int s0 = csr[e];
        short4v v0 = *(const short4v*)(basep + (size_t)s0 * rowW + colOff);
        m0 = fmaxf(m0, bitsf(v0[0]));
        m1 = fmaxf(m1, bitsf(v0[1]));
        m2 = fmaxf(m2, bitsf(v0[2]));
        m3 = fmaxf(m3, bitsf(v0[3]));
    }
    if (beg == end) { m0 = m1 = m2 = m3 = 0.f; }
    short4v o;
    o[0] = bfbits(m0); o[1] = bfbits(m1); o[2] = bfbits(m2); o[3] = bfbits(m3);
    *(short4v*)((short*)agg + (size_t)n * 256 + lane * 4) = o;
}

// ---------------------------------------------------------------------------
// per-segment sum pool over h [N,192] + fc dot -> scores [512]
// ---------------------------------------------------------------------------
__global__ __launch_bounds__(256) void pool_fc(
    const bf16* __restrict__ h, const int* __restrict__ sep,
    const float* __restrict__ fc_w, float* __restrict__ out)
{
    __shared__ float red[256];
    int b = blockIdx.x, t = threadIdx.x;
    int r0 = (b == 0) ? 0 : sep[b - 1];
    int r1 = sep[b];
    float s0 = 0.f, s1 = 0.f, s2 = 0.f, s3 = 0.f;
    if (t < 192) {
        int r = r0;
        for (; r + 3 < r1; r += 4) {
            s0 += __bfloat162float(h[(size_t)r * 192 + t]);
            s1 += __bfloat162float(h[(size_t)(r + 1) * 192 + t]);
            s2 += __bfloat162float(h[(size_t)(r + 2) * 192 + t]);
            s3 += __bfloat162float(h[(size_t)(r + 3) * 192 + t]);
        }
        for (; r < r1; ++r) s0 += __bfloat162float(h[(size_t)r * 192 + t]);
    }
    red[t] = (t < 192) ? (s0 + s1 + s2 + s3) * fc_w[t] : 0.f;
    __syncthreads();
    #pragma unroll
    for (int st = 128; st > 0; st >>= 1) {
        if (t < st) red[t] += red[t + st];
        __syncthreads();
    }
    if (t == 0) out[b] = red[0];
}

// diagnostic: report ws_size (MiB) through the output if workspace too small
__global__ void report_ws(float* __restrict__ out, float mb)
{
    out[blockIdx.x * 256 + threadIdx.x] = mb;
}

// ---------------------------------------------------------------------------
extern "C" void kernel_launch(void* const* d_in, const int* in_sizes, int n_in,
                              void* d_out, int out_size, void* d_ws, size_t ws_size,
                              hipStream_t stream)
{
    const float* node_features = (const float*)d_in[0];
    const float* node_config   = (const float*)d_in[1];
    const int*   node_sep      = (const int*)d_in[2];
    const int*   node_ops      = (const int*)d_in[3];
    const int*   edges         = (const int*)d_in[4];
    // d_in[5] = batches (unused by the reference math)
    const float* emb    = (const float*)d_in[6];
    const float* nf_w1  = (const float*)d_in[7];
    const float* nf_b1  = (const float*)d_in[8];
    const float* nf_w2  = (const float*)d_in[9];
    const float* nf_b2  = (const float*)d_in[10];
    const float* cf_w1  = (const float*)d_in[11];
    const float* cf_b1  = (const float*)d_in[12];
    const float* cf_w2  = (const float*)d_in[13];
    const float* cf_b2  = (const float*)d_in[14];
    const float* pre_w1 = (const float*)d_in[15];
    const float* pre_b1 = (const float*)d_in[16];
    const float* pre_w2 = (const float*)d_in[17];
    const float* pre_b2 = (const float*)d_in[18];
    const float* sage_wl= (const float*)d_in[19];
    const float* sage_bl= (const float*)d_in[20];
    const float* sage_wr= (const float*)d_in[21];
    const float* mlp_w1 = (const float*)d_in[22];
    const float* mlp_b1 = (const float*)d_in[23];
    const float* mlp_w2 = (const float*)d_in[24];
    const float* mlp_b2 = (const float*)d_in[25];
    const float* fc_w   = (const float*)d_in[26];

    const size_t N = NNODES;

    // Wt blob offsets (elements); total 584,960 bf16
    const size_t WT_NF1  = 0;                          // [176][176]
    const size_t WT_NF2  = WT_NF1  + 176 * 176;        // [192][176]
    const size_t WT_PRE1 = WT_NF2  + 192 * 176;        // [192][256]
    const size_t WT_PRE2 = WT_PRE1 + 192 * 256;        // [192][192]
    const size_t WT_SAGE = WT_PRE2 + 192 * 192;        // 2x [256][512]
    const size_t WT_MLP1 = WT_SAGE + 2 * 256 * 512;    // 2x [192][256]
    const size_t WT_MLP2 = WT_MLP1 + 2 * 192 * 256;    // 2x [192][192]
    const size_t WT_TOT  = WT_MLP2 + 2 * 192 * 192;

    // workspace: bf16 activations | Wt bf16 | CSR ints  (~391 MiB)
    const size_t fl_bytes  = N * 768 * sizeof(bf16);
    const size_t wt_bytes  = WT_TOT * 2;
    const size_t int_elems = (N + 1) + N + N + NEDGES + 256;
    const size_t needed    = fl_bytes + wt_bytes + int_elems * 4;
    if (ws_size < needed) {
        report_ws<<<2, 256, 0, stream>>>((float*)d_out,
                                         (float)((double)ws_size / 1048576.0));
        return;
    }

    bf16* cf   = (bf16*)d_ws;                   // [N,64]
    bf16* h    = cf   + N * 64;                 // [N,192]
    bf16* bufA = h    + N * 192;                // [N,256]  t1/t2/agg
    bf16* bufB = bufA + N * 256;                // [N,256]  x/z
    short* wt  = (short*)(bufB + N * 256);      // Wt blobs (1.14 MB, 16B-aligned)
    int* offsets = (int*)(wt + WT_TOT);         // [N+1]
    int* indeg   = offsets + (N + 1);           // [N]
    int* cursor  = indeg + N;                   // [N]
    int* csr     = cursor + N;                  // [E]
    int* bsums   = csr + NEDGES;                // [256]

    const int* esrc = edges;            // edges[0, :]
    const int* edst = edges + NEDGES;   // edges[1, :]

    dim3 blk(256);
    dim3 blk512(512);
    const int GB = NNODES / 128;        // 2048 gemm blocks

    // ---- fused weight prep (one launch, 10 transposes) ----
    {
        PrepJobs jobs;
        auto set = [&](int i, const float* wa, const float* wb, int kw, int K,
                       int OUT, size_t off) {
            jobs.wa[i] = wa; jobs.wb[i] = wb; jobs.kw[i] = kw;
            jobs.K[i] = K; jobs.OUT[i] = OUT; jobs.off[i] = (long)off;
        };
        set(0, nf_w1, nullptr, 176, 176, 176, WT_NF1);
        set(1, nf_w2, nullptr, 176, 176, 192, WT_NF2);
        set(2, pre_w1, nullptr, 256, 256, 192, WT_PRE1);
        set(3, pre_w2, nullptr, 192, 192, 192, WT_PRE2);
        set(4, sage_wl,               sage_wr,               256, 512, 256, WT_SAGE);
        set(5, sage_wl + 256 * 256,   sage_wr + 256 * 256,   256, 512, 256, WT_SAGE + 256 * 512);
        set(6, mlp_w1,                nullptr, 256, 256, 192, WT_MLP1);
        set(7, mlp_w1 + 256 * 192,    nullptr, 256, 256, 192, WT_MLP1 + 192 * 256);
        set(8, mlp_w2,                nullptr, 192, 192, 192, WT_MLP2);
        set(9, mlp_w2 + 192 * 192,    nullptr, 192, 192, 192, WT_MLP2 + 192 * 192);
        prep_all<<<dim3(2, 256, 10), blk, 0, stream>>>(jobs, wt);
    }

    // ---- config-feature MLP -> cf [N,64] ----
    cf_mlp<<<NNODES / 256, blk, 0, stream>>>(node_config, cf_w1, cf_b1, cf_w2, cf_b2, cf);

    // ---- node-feature MLP ----
    mfma_gemm<float, 192><<<GB, blk512, 0, stream>>>(
        node_features, 112, emb, 64, (const float*)nullptr, 0, node_ops,
        wt + WT_NF1, nf_b1, nullptr, bufA, 176, 176, 0.01f);
    mfma_gemm<bf16, 192><<<GB, blk512, 0, stream>>>(
        bufA, 176, (const bf16*)nullptr, 0, (const bf16*)nullptr, 0, nullptr,
        wt + WT_NF2, nf_b2, nullptr, bufB, 176, 192, 0.01f);

    // ---- prenet ----
    mfma_gemm<bf16, 192><<<GB, blk512, 0, stream>>>(
        cf, 64, bufB, 192, (const bf16*)nullptr, 0, nullptr,
        wt + WT_PRE1, pre_b1, nullptr, bufA, 256, 192, 0.2f);
    mfma_gemm<bf16, 192><<<GB, blk512, 0, stream>>>(
        bufA, 192, (const bf16*)nullptr, 0, (const bf16*)nullptr, 0, nullptr,
        wt + WT_PRE2, pre_b2, nullptr, h, 192, 192, 0.2f);

    // ---- CSR build ----
    zero_ints<<<NNODES / 256, blk, 0, stream>>>(indeg, NNODES);
    count_deg<<<NEDGES / 256, blk, 0, stream>>>(edst, indeg);
    scan_block<<<NNODES / 1024, blk, 0, stream>>>(indeg, offsets, bsums);
    scan_tops<<<1, blk, 0, stream>>>(bsums);
    scan_fix<<<NNODES / 256, blk, 0, stream>>>(offsets, bsums, cursor);
    scatter_edges<<<NEDGES / 256, blk, 0, stream>>>(esrc, edst, cursor, csr);

    // ---- 2 x (SAGE-max + MLP + residual) ----
    for (int l = 0; l < 2; ++l) {
        sage_agg<<<NNODES / 4, blk, 0, stream>>>(offsets, csr, cf, h, bufA);
        // z = [agg | cf | h] @ [Wl;Wr] + bl   (K=512, identity act)
        mfma_gemm<bf16, 256><<<GB, blk512, 0, stream>>>(
            bufA, 256, cf, 64, h, 192, nullptr,
            wt + WT_SAGE + (size_t)l * 256 * 512, sage_bl + (size_t)l * 256,
            nullptr, bufB, 512, 256, 1.0f);
        mfma_gemm<bf16, 192><<<GB, blk512, 0, stream>>>(
            bufB, 256, (const bf16*)nullptr, 0, (const bf16*)nullptr, 0, nullptr,
            wt + WT_MLP1 + (size_t)l * 192 * 256, mlp_b1 + (size_t)l * 192,
            nullptr, bufA, 256, 192, 0.2f);
        mfma_gemm<bf16, 192><<<GB, blk512, 0, stream>>>(
            bufA, 192, (const bf16*)nullptr, 0, (const bf16*)nullptr, 0, nullptr,
            wt + WT_MLP2 + (size_t)l * 192 * 192, mlp_b2 + (size_t)l * 192,
            h, h, 192, 192, 0.2f);
    }

    // ---- pooled segment sums + fc -> scores [512] ----
    pool_fc<<<NSEG, blk, 0, stream>>>(h, node_sep, fc_w, (float*)d_out);
}

// Round 10
// 1377.071 us; speedup vs baseline: 9.2800x; 1.0142x over previous
//
#include <hip/hip_runtime.h>
#include <hip/hip_bf16.h>
#include <math.h>

#define NNODES 262144
#define NEDGES 524288
#define NSEG   512      // B*C segments

typedef __hip_bfloat16 bf16;
typedef __attribute__((ext_vector_type(8))) short short8;   // 8 bf16 = 4 VGPR
typedef __attribute__((ext_vector_type(4))) short short4v;  // 4 bf16 = 2 VGPR
typedef __attribute__((ext_vector_type(4))) float f32x4;

__device__ __forceinline__ short bfbits(float f) {
    return __builtin_bit_cast(short, (__bf16)f);
}
__device__ __forceinline__ float bitsf(short s) {
    unsigned u = ((unsigned)(unsigned short)s) << 16;
    return __builtin_bit_cast(float, u);
}

// load 8 contiguous virtual-K elements as bf16 bits (16B-aligned: all widths %8==0)
__device__ __forceinline__ short8 ld8(const bf16* p, size_t off) {
    return *(const short8*)((const short*)p + off);
}
__device__ __forceinline__ short8 ld8(const float* p, size_t off) {
    const float4* q = (const float4*)(p + off);
    float4 a = q[0], b = q[1];
    short8 r;
    r[0] = bfbits(a.x); r[1] = bfbits(a.y); r[2] = bfbits(a.z); r[3] = bfbits(a.w);
    r[4] = bfbits(b.x); r[5] = bfbits(b.y); r[6] = bfbits(b.z); r[7] = bfbits(b.w);
    return r;
}

// ---------------------------------------------------------------------------
// Fused weight prep: one launch transposes all 10 matrices to Wt[OUT][K] bf16.
// grid (2, 256, 10): blockIdx.x = k-chunk, .y = out col, .z = job.
// ---------------------------------------------------------------------------
struct PrepJobs {
    const float* wa[10];
    const float* wb[10];
    int kw[10]; int K[10]; int OUT[10]; long off[10];
};

__global__ void prep_all(PrepJobs jobs, short* __restrict__ wt)
{
    int j = blockIdx.z;
    int k = blockIdx.x * 256 + threadIdx.x;
    int c = blockIdx.y;
    int K = jobs.K[j], OUT = jobs.OUT[j];
    if (k < K && c < OUT) {
        int kw = jobs.kw[j];
        float v = (k < kw) ? jobs.wa[j][(size_t)k * OUT + c]
                           : jobs.wb[j][(size_t)(k - kw) * OUT + c];
        wt[jobs.off[j] + (size_t)c * K + k] = bfbits(v);
    }
}

// ---------------------------------------------------------------------------
// MFMA GEMM v4: out[n,:OUT] = res + lrelu_alpha( A[n,:K] @ W + bias ), W = Wt^T
// 512 threads (8 waves, 2x4), tile 128 rows x BN cols, BK=32.
// - LDS: 64B row pitch (32 shorts), 16B-chunk XOR swizzle c^=((row>>1)&3)
//   -> bank-conflict-free ds_read_b128/ds_write_b128 (T2).
// - Double-buffered LDS, ONE barrier per K-step: barrier; issue loads(t+1);
//   compute buf[t&1]; write buf[(t+1)&1] (T3/T14).
// SWAPPED mfma operands -> D^T layout -> 8B coalesced stores.
// ---------------------------------------------------------------------------
template<typename TA, int BN>
__global__ __launch_bounds__(512, 4) void mfma_gemm(
    const TA* __restrict__ A0, int w0,
    const TA* __restrict__ A1, int w1,
    const TA* __restrict__ A2, int w2,
    const int*   __restrict__ gidx,
    const short* __restrict__ Wt,
    const float* __restrict__ bias,
    const bf16*  __restrict__ res,
    bf16* __restrict__ out,
    int K, int OUT, float alpha)
{
    constexpr int NRW = BN / 64;              // n-frags per wave
    constexpr int NB  = (BN * 4 + 511) / 512; // B chunks per thread
    __shared__ short As[2][128 * 32];
    __shared__ short Bs[2][BN * 32];
    __shared__ float biasLds[BN];

    const int tid  = threadIdx.x;
    const int lane = tid & 63;
    const int wid  = tid >> 6;          // 0..7
    const int row0 = blockIdx.x * 128;
    const int wr   = (wid >> 2) * 64;       // wave row offset (0,64)
    const int wc   = (wid & 3) * (BN / 4);  // wave col offset
    const int fr   = lane & 15;
    const int fc   = lane >> 4;

    if (tid < BN) biasLds[tid] = (tid < OUT) ? bias[tid] : 0.f;

    // fixed per-thread staging coordinates
    const int ar  = tid >> 2;           // A row
    const int akl = (tid & 3) * 8;      // A k-offset (shorts)
    // swizzled LDS offsets (chunk ^= (row>>1)&3)
    const int aWr = ar * 32 + (((tid & 3) ^ ((ar >> 1) & 3)) * 8);
    const int sRd = ((fc ^ ((fr >> 1) & 3)) * 8);   // read chunk offset

    auto loadA = [&](int k0) -> short8 {
        int gk = k0 + akl;
        short8 v{};
        if (gk < K) {
            int n = row0 + ar;
            if (gk < w0) v = ld8(A0, (size_t)n * w0 + gk);
            else {
                int k1 = gk - w0;
                if (k1 < w1) {
                    int rr = gidx ? gidx[n] : n;
                    v = ld8(A1, (size_t)rr * w1 + k1);
                } else {
                    v = ld8(A2, (size_t)n * w2 + (k1 - w1));
                }
            }
        }
        return v;
    };
    auto loadB = [&](int k0, int i) -> short8 {
        int f = i * 512 + tid;
        short8 v{};
        if (f < BN * 4) {
            int c  = f >> 2;
            int gk = k0 + (f & 3) * 8;
            if (gk < K && c < OUT) v = *(const short8*)&Wt[(size_t)c * K + gk];
        }
        return v;
    };
    auto writeAB = [&](int p, short8 a, short8* b) {
        *(short8*)&As[p][aWr] = a;
        #pragma unroll
        for (int i = 0; i < NB; ++i) {
            int f = i * 512 + tid;
            if (f < BN * 4) {
                int cc = f >> 2;
                int cs = ((f & 3) ^ ((cc >> 1) & 3)) * 8;
                *(short8*)&Bs[p][cc * 32 + cs] = b[i];
            }
        }
    };

    f32x4 acc[NRW][4];
    #pragma unroll
    for (int nr = 0; nr < NRW; ++nr)
        #pragma unroll
        for (int m = 0; m < 4; ++m) acc[nr][m] = f32x4{0.f, 0.f, 0.f, 0.f};

    // prologue: load + stage K-step 0 into buf 0
    {
        short8 a0 = loadA(0);
        short8 b0[NB];
        #pragma unroll
        for (int i = 0; i < NB; ++i) b0[i] = loadB(0, i);
        writeAB(0, a0, b0);
    }

    const int nsteps = (K + 31) / 32;
    for (int s = 0; s < nsteps; ++s) {
        __syncthreads();                    // buf[s&1] ready; prev reads done
        int k0 = s * 32;
        // issue next K-step's global loads (latency hides under compute)
        short8 aN{};
        short8 bN[NB];
        #pragma unroll
        for (int i = 0; i < NB; ++i) bN[i] = short8{};
        bool more = (k0 + 32 < K);
        if (more) {
            aN = loadA(k0 + 32);
            #pragma unroll
            for (int i = 0; i < NB; ++i) bN[i] = loadB(k0 + 32, i);
        }
        // compute from buf[s&1]
        const short* as = As[s & 1];
        const short* bs = Bs[s & 1];
        short8 af[4];
        #pragma unroll
        for (int m = 0; m < 4; ++m)
            af[m] = *(const short8*)&as[(wr + m * 16 + fr) * 32 + sRd];
        #pragma unroll
        for (int nr = 0; nr < NRW; ++nr) {
            short8 bfr = *(const short8*)&bs[(wc + nr * 16 + fr) * 32 + sRd];
            #pragma unroll
            for (int m = 0; m < 4; ++m)
                acc[nr][m] = __builtin_amdgcn_mfma_f32_16x16x32_bf16(
                    bfr, af[m], acc[nr][m], 0, 0, 0);
        }
        // stage next step into the other buffer (no barrier needed here:
        // all waves are between barrier(s) and barrier(s+1); reads use
        // parity s, writes parity s+1)
        if (more) writeAB((s + 1) & 1, aN, bN);
    }
    // ---- epilogue: D^T layout -> lane holds row (row0+wr+m*16+fr),
    //      cols c0..c0+3 with c0 = wc+nr*16+fc*4. One 8B store per frag. ----
    #pragma unroll
    for (int nr = 0; nr < NRW; ++nr) {
        int c0 = wc + nr * 16 + fc * 4;
        if (c0 < OUT) {
            #pragma unroll
            for (int m = 0; m < 4; ++m) {
                int r = row0 + wr + m * 16 + fr;
                size_t base = (size_t)r * OUT + c0;
                short4v o;
                if (res) {
                    short4v rv = *(const short4v*)((const short*)res + base);
                    #pragma unroll
                    for (int j = 0; j < 4; ++j) {
                        float v = acc[nr][m][j] + biasLds[c0 + j];
                        v = (v > 0.f) ? v : alpha * v;
                        o[j] = bfbits(v + bitsf(rv[j]));
                    }
                } else {
                    #pragma unroll
                    for (int j = 0; j < 4; ++j) {
                        float v = acc[nr][m][j] + biasLds[c0 + j];
                        v = (v > 0.f) ? v : alpha * v;
                        o[j] = bfbits(v);
                    }
                }
                *(short4v*)((short*)out + base) = o;
            }
        }
    }
}

// ---------------------------------------------------------------------------
// config-feature MLP: 14 -> 14 (lrelu .01) -> 64 (lrelu .01), one thread/node
// ---------------------------------------------------------------------------
__global__ __launch_bounds__(256) void cf_mlp(
    const float* __restrict__ ncf,
    const float* __restrict__ w1, const float* __restrict__ b1,
    const float* __restrict__ w2, const float* __restrict__ b2,
    bf16* __restrict__ cf)
{
    __shared__ float W1s[196], B1s[14], W2s[896], B2s[64];
    int t = threadIdx.x;
    for (int i = t; i < 196; i += 256) W1s[i] = w1[i];
    for (int i = t; i < 896; i += 256) W2s[i] = w2[i];
    if (t < 14) B1s[t] = b1[t];
    if (t >= 32 && t < 96) B2s[t - 32] = b2[t - 32];
    __syncthreads();

    int n = blockIdx.x * 256 + t;
    float in[14], hid[14];
    {   // vectorized input: 14 fp32 = 7 x float2 (8B-aligned: 56B rows)
        const float2* p2 = (const float2*)(ncf + (size_t)n * 14);
        #pragma unroll
        for (int k = 0; k < 7; ++k) {
            float2 v = p2[k];
            in[2 * k] = v.x; in[2 * k + 1] = v.y;
        }
    }
    #pragma unroll
    for (int j = 0; j < 14; ++j) {
        float s = B1s[j];
        #pragma unroll
        for (int k = 0; k < 14; ++k) s += in[k] * W1s[k * 14 + j];
        hid[j] = (s > 0.f) ? s : 0.01f * s;
    }
    #pragma unroll 4
    for (int j = 0; j < 64; ++j) {
        float s = B2s[j];
        #pragma unroll
        for (int k = 0; k < 14; ++k) s += hid[k] * W2s[k * 64 + j];
        s = (s > 0.f) ? s : 0.01f * s;
        cf[(size_t)n * 64 + j] = __float2bfloat16(s);
    }
}

// ---------------------------------------------------------------------------
// CSR build: zero -> indeg count -> 3-phase exclusive scan -> scatter
// ---------------------------------------------------------------------------
__global__ void zero_ints(int* __restrict__ p, int n)
{
    int i = blockIdx.x * 256 + threadIdx.x;
    if (i < n) p[i] = 0;
}

__global__ void count_deg(const int* __restrict__ dst, int* __restrict__ indeg)
{
    int e = blockIdx.x * 256 + threadIdx.x;
    atomicAdd(&indeg[dst[e]], 1);
}

__global__ __launch_bounds__(256) void scan_block(
    const int* __restrict__ in, int* __restrict__ part, int* __restrict__ bsums)
{
    __shared__ int sh[256];
    int t = threadIdx.x, b = blockIdx.x;
    int base = b * 1024 + t * 4;
    int v0 = in[base], v1 = in[base + 1], v2 = in[base + 2], v3 = in[base + 3];
    int s = v0 + v1 + v2 + v3;
    sh[t] = s; __syncthreads();
    #pragma unroll
    for (int off = 1; off < 256; off <<= 1) {
        int x = (t >= off) ? sh[t - off] : 0;
        __syncthreads();
        sh[t] += x;
        __syncthreads();
    }
    int excl = sh[t] - s;
    if (t == 255) bsums[b] = sh[t];
    part[base]     = excl;
    part[base + 1] = excl + v0;
    part[base + 2] = excl + v0 + v1;
    part[base + 3] = excl + v0 + v1 + v2;
}

__global__ __launch_bounds__(256) void scan_tops(int* __restrict__ bsums)
{
    __shared__ int sh[256];
    int t = threadIdx.x;
    int s = bsums[t];
    sh[t] = s; __syncthreads();
    #pragma unroll
    for (int off = 1; off < 256; off <<= 1) {
        int x = (t >= off) ? sh[t - off] : 0;
        __syncthreads();
        sh[t] += x;
        __syncthreads();
    }
    bsums[t] = sh[t] - s;   // exclusive
}

__global__ void scan_fix(int* __restrict__ offsets, const int* __restrict__ bsums,
                         int* __restrict__ cursor)
{
    int i = blockIdx.x * 256 + threadIdx.x;
    int v = offsets[i] + bsums[i >> 10];
    offsets[i] = v;
    cursor[i]  = v;
    if (i == 0) offsets[NNODES] = NEDGES;
}

__global__ void scatter_edges(const int* __restrict__ src, const int* __restrict__ dst,
                              int* __restrict__ cursor, int* __restrict__ csr)
{
    int e = blockIdx.x * 256 + threadIdx.x;
    int pos = atomicAdd(&cursor[dst[e]], 1);
    csr[pos] = src[e];
}

// ---------------------------------------------------------------------------
// SAGE max-aggregation v2: one wave per dst node; lane covers 4 consecutive
// cols of y=[cf(64)|h(192)] -> ONE 8B load per edge per lane.
// 2-edge unroll to overlap gather latency. Empty neighborhood -> 0.
// ---------------------------------------------------------------------------
__global__ __launch_bounds__(256) void sage_agg(
    const int* __restrict__ offsets, const int* __restrict__ csr,
    const bf16* __restrict__ cf, const bf16* __restrict__ h,
    bf16* __restrict__ agg)
{
    int wid = threadIdx.x >> 6, lane = threadIdx.x & 63;
    int n = blockIdx.x * 4 + wid;
    int beg = offsets[n], end = offsets[n + 1];

    bool isCf = lane < 16;
    const short* basep = isCf ? (const short*)cf : (const short*)h;
    int rowW   = isCf ? 64 : 192;
    int colOff = isCf ? lane * 4 : lane * 4 - 64;

    float m0 = -3.4e38f, m1 = m0, m2 = m0, m3 = m0;
    int e = beg;
    for (; e + 1 < end; e += 2) {
        int s0 = csr[e], s1 = csr[e + 1];
        short4v v0 = *(const short4v*)(basep + (size_t)s0 * rowW + colOff);
        short4v v1 = *(const short4v*)(basep + (size_t)s1 * rowW + colOff);
        m0 = fmaxf(fmaxf(m0, bitsf(v0[0])), bitsf(v1[0]));
        m1 = fmaxf(fmaxf(m1, bitsf(v0[1])), bitsf(v1[1]));
        m2 = fmaxf(fmaxf(m2, bitsf(v0[2])), bitsf(v1[2]));
        m3 = fmaxf(fmaxf(m3, bitsf(v0[3])), bitsf(v1[3]));
    }
    if (e < end) {
        int s0 = csr[e];
        short4v v0 = *(const short4v*)(basep + (size_t)s0 * rowW + colOff);
        m0 = fmaxf(m0, bitsf(v0[0]));
        m1 = fmaxf(m1, bitsf(v0[1]));
        m2 = fmaxf(m2, bitsf(v0[2]));
        m3 = fmaxf(m3, bitsf(v0[3]));
    }
    if (beg == end) { m0 = m1 = m2 = m3 = 0.f; }
    short4v o;
    o[0] = bfbits(m0); o[1] = bfbits(m1); o[2] = bfbits(m2); o[3] = bfbits(m3);
    *(short4v*)((short*)agg + (size_t)n * 256 + lane * 4) = o;
}

// ---------------------------------------------------------------------------
// per-segment sum pool over h [N,192] + fc dot -> scores [512]
// ---------------------------------------------------------------------------
__global__ __launch_bounds__(256) void pool_fc(
    const bf16* __restrict__ h, const int* __restrict__ sep,
    const float* __restrict__ fc_w, float* __restrict__ out)
{
    __shared__ float red[256];
    int b = blockIdx.x, t = threadIdx.x;
    int r0 = (b == 0) ? 0 : sep[b - 1];
    int r1 = sep[b];
    float s0 = 0.f, s1 = 0.f, s2 = 0.f, s3 = 0.f;
    if (t < 192) {
        int r = r0;
        for (; r + 3 < r1; r += 4) {
            s0 += __bfloat162float(h[(size_t)r * 192 + t]);
            s1 += __bfloat162float(h[(size_t)(r + 1) * 192 + t]);
            s2 += __bfloat162float(h[(size_t)(r + 2) * 192 + t]);
            s3 += __bfloat162float(h[(size_t)(r + 3) * 192 + t]);
        }
        for (; r < r1; ++r) s0 += __bfloat162float(h[(size_t)r * 192 + t]);
    }
    red[t] = (t < 192) ? (s0 + s1 + s2 + s3) * fc_w[t] : 0.f;
    __syncthreads();
    #pragma unroll
    for (int st = 128; st > 0; st >>= 1) {
        if (t < st) red[t] += red[t + st];
        __syncthreads();
    }
    if (t == 0) out[b] = red[0];
}

// diagnostic: report ws_size (MiB) through the output if workspace too small
__global__ void report_ws(float* __restrict__ out, float mb)
{
    out[blockIdx.x * 256 + threadIdx.x] = mb;
}

// ---------------------------------------------------------------------------
extern "C" void kernel_launch(void* const* d_in, const int* in_sizes, int n_in,
                              void* d_out, int out_size, void* d_ws, size_t ws_size,
                              hipStream_t stream)
{
    const float* node_features = (const float*)d_in[0];
    const float* node_config   = (const float*)d_in[1];
    const int*   node_sep      = (const int*)d_in[2];
    const int*   node_ops      = (const int*)d_in[3];
    const int*   edges         = (const int*)d_in[4];
    // d_in[5] = batches (unused by the reference math)
    const float* emb    = (const float*)d_in[6];
    const float* nf_w1  = (const float*)d_in[7];
    const float* nf_b1  = (const float*)d_in[8];
    const float* nf_w2  = (const float*)d_in[9];
    const float* nf_b2  = (const float*)d_in[10];
    const float* cf_w1  = (const float*)d_in[11];
    const float* cf_b1  = (const float*)d_in[12];
    const float* cf_w2  = (const float*)d_in[13];
    const float* cf_b2  = (const float*)d_in[14];
    const float* pre_w1 = (const float*)d_in[15];
    const float* pre_b1 = (const float*)d_in[16];
    const float* pre_w2 = (const float*)d_in[17];
    const float* pre_b2 = (const float*)d_in[18];
    const float* sage_wl= (const float*)d_in[19];
    const float* sage_bl= (const float*)d_in[20];
    const float* sage_wr= (const float*)d_in[21];
    const float* mlp_w1 = (const float*)d_in[22];
    const float* mlp_b1 = (const float*)d_in[23];
    const float* mlp_w2 = (const float*)d_in[24];
    const float* mlp_b2 = (const float*)d_in[25];
    const float* fc_w   = (const float*)d_in[26];

    const size_t N = NNODES;

    // Wt blob offsets (elements); total 584,960 bf16
    const size_t WT_NF1  = 0;                          // [176][176]
    const size_t WT_NF2  = WT_NF1  + 176 * 176;        // [192][176]
    const size_t WT_PRE1 = WT_NF2  + 192 * 176;        // [192][256]
    const size_t WT_PRE2 = WT_PRE1 + 192 * 256;        // [192][192]
    const size_t WT_SAGE = WT_PRE2 + 192 * 192;        // 2x [256][512]
    const size_t WT_MLP1 = WT_SAGE + 2 * 256 * 512;    // 2x [192][256]
    const size_t WT_MLP2 = WT_MLP1 + 2 * 192 * 256;    // 2x [192][192]
    const size_t WT_TOT  = WT_MLP2 + 2 * 192 * 192;

    // workspace: bf16 activations | Wt bf16 | CSR ints  (~391 MiB)
    const size_t fl_bytes  = N * 768 * sizeof(bf16);
    const size_t wt_bytes  = WT_TOT * 2;
    const size_t int_elems = (N + 1) + N + N + NEDGES + 256;
    const size_t needed    = fl_bytes + wt_bytes + int_elems * 4;
    if (ws_size < needed) {
        report_ws<<<2, 256, 0, stream>>>((float*)d_out,
                                         (float)((double)ws_size / 1048576.0));
        return;
    }

    bf16* cf   = (bf16*)d_ws;                   // [N,64]
    bf16* h    = cf   + N * 64;                 // [N,192]
    bf16* bufA = h    + N * 192;                // [N,256]  t1/t2/agg
    bf16* bufB = bufA + N * 256;                // [N,256]  x/z
    short* wt  = (short*)(bufB + N * 256);      // Wt blobs (1.14 MB, 16B-aligned)
    int* offsets = (int*)(wt + WT_TOT);         // [N+1]
    int* indeg   = offsets + (N + 1);           // [N]
    int* cursor  = indeg + N;                   // [N]
    int* csr     = cursor + N;                  // [E]
    int* bsums   = csr + NEDGES;                // [256]

    const int* esrc = edges;            // edges[0, :]
    const int* edst = edges + NEDGES;   // edges[1, :]

    dim3 blk(256);
    dim3 blk512(512);
    const int GB = NNODES / 128;        // 2048 gemm blocks

    // ---- fused weight prep (one launch, 10 transposes) ----
    {
        PrepJobs jobs;
        auto set = [&](int i, const float* wa, const float* wb, int kw, int K,
                       int OUT, size_t off) {
            jobs.wa[i] = wa; jobs.wb[i] = wb; jobs.kw[i] = kw;
            jobs.K[i] = K; jobs.OUT[i] = OUT; jobs.off[i] = (long)off;
        };
        set(0, nf_w1, nullptr, 176, 176, 176, WT_NF1);
        set(1, nf_w2, nullptr, 176, 176, 192, WT_NF2);
        set(2, pre_w1, nullptr, 256, 256, 192, WT_PRE1);
        set(3, pre_w2, nullptr, 192, 192, 192, WT_PRE2);
        set(4, sage_wl,               sage_wr,               256, 512, 256, WT_SAGE);
        set(5, sage_wl + 256 * 256,   sage_wr + 256 * 256,   256, 512, 256, WT_SAGE + 256 * 512);
        set(6, mlp_w1,                nullptr, 256, 256, 192, WT_MLP1);
        set(7, mlp_w1 + 256 * 192,    nullptr, 256, 256, 192, WT_MLP1 + 192 * 256);
        set(8, mlp_w2,                nullptr, 192, 192, 192, WT_MLP2);
        set(9, mlp_w2 + 192 * 192,    nullptr, 192, 192, 192, WT_MLP2 + 192 * 192);
        prep_all<<<dim3(2, 256, 10), blk, 0, stream>>>(jobs, wt);
    }

    // ---- config-feature MLP -> cf [N,64] ----
    cf_mlp<<<NNODES / 256, blk, 0, stream>>>(node_config, cf_w1, cf_b1, cf_w2, cf_b2, cf);

    // ---- node-feature MLP ----
    mfma_gemm<float, 192><<<GB, blk512, 0, stream>>>(
        node_features, 112, emb, 64, (const float*)nullptr, 0, node_ops,
        wt + WT_NF1, nf_b1, nullptr, bufA, 176, 176, 0.01f);
    mfma_gemm<bf16, 192><<<GB, blk512, 0, stream>>>(
        bufA, 176, (const bf16*)nullptr, 0, (const bf16*)nullptr, 0, nullptr,
        wt + WT_NF2, nf_b2, nullptr, bufB, 176, 192, 0.01f);

    // ---- prenet ----
    mfma_gemm<bf16, 192><<<GB, blk512, 0, stream>>>(
        cf, 64, bufB, 192, (const bf16*)nullptr, 0, nullptr,
        wt + WT_PRE1, pre_b1, nullptr, bufA, 256, 192, 0.2f);
    mfma_gemm<bf16, 192><<<GB, blk512, 0, stream>>>(
        bufA, 192, (const bf16*)nullptr, 0, (const bf16*)nullptr, 0, nullptr,
        wt + WT_PRE2, pre_b2, nullptr, h, 192, 192, 0.2f);

    // ---- CSR build ----
    zero_ints<<<NNODES / 256, blk, 0, stream>>>(indeg, NNODES);
    count_deg<<<NEDGES / 256, blk, 0, stream>>>(edst, indeg);
    scan_block<<<NNODES / 1024, blk, 0, stream>>>(indeg, offsets, bsums);
    scan_tops<<<1, blk, 0, stream>>>(bsums);
    scan_fix<<<NNODES / 256, blk, 0, stream>>>(offsets, bsums, cursor);
    scatter_edges<<<NEDGES / 256, blk, 0, stream>>>(esrc, edst, cursor, csr);

    // ---- 2 x (SAGE-max + MLP + residual) ----
    for (int l = 0; l < 2; ++l) {
        sage_agg<<<NNODES / 4, blk, 0, stream>>>(offsets, csr, cf, h, bufA);
        // z = [agg | cf | h] @ [Wl;Wr] + bl   (K=512, identity act)
        mfma_gemm<bf16, 256><<<GB, blk512, 0, stream>>>(
            bufA, 256, cf, 64, h, 192, nullptr,
            wt + WT_SAGE + (size_t)l * 256 * 512, sage_bl + (size_t)l * 256,
            nullptr, bufB, 512, 256, 1.0f);
        mfma_gemm<bf16, 192><<<GB, blk512, 0, stream>>>(
            bufB, 256, (const bf16*)nullptr, 0, (const bf16*)nullptr, 0, nullptr,
            wt + WT_MLP1 + (size_t)l * 192 * 256, mlp_b1 + (size_t)l * 192,
            nullptr, bufA, 256, 192, 0.2f);
        mfma_gemm<bf16, 192><<<GB, blk512, 0, stream>>>(
            bufA, 192, (const bf16*)nullptr, 0, (const bf16*)nullptr, 0, nullptr,
            wt + WT_MLP2 + (size_t)l * 192 * 192, mlp_b2 + (size_t)l * 192,
            h, h, 192, 192, 0.2f);
    }

    // ---- pooled segment sums + fc -> scores [512] ----
    pool_fc<<<NSEG, blk, 0, stream>>>(h, node_sep, fc_w, (float*)d_out);
}